// Round 11
// baseline (3616.089 us; speedup 1.0000x reference)
//
#include <hip/hip_runtime.h>

// ALIGNN forward on MI355X. Round 10: pipelined line phase — line_step
// kernel runs fused(chunk c) and m/u3-GEMM(chunk c+1) in ONE launch with
// double-buffered mchunk/u3c (24 chunks of 2048 nodes; memory-neutral).

typedef unsigned short bfu;
typedef __attribute__((ext_vector_type(8))) short short8;   // 8 bf16
typedef __attribute__((ext_vector_type(4))) float floatx4;  // MFMA C/D

#define CHN 2048        // dst nodes per line-graph chunk (24 chunks)
#define CHCAP 12288     // row capacity per chunk (mean 10922, +13 sigma)
#define HH 65536        // 256*256

__device__ __forceinline__ float bf2f(bfu u) {
  union { unsigned u; float f; } x; x.u = ((unsigned)u) << 16; return x.f;
}
__device__ __forceinline__ bfu f2bf(float f) {
  union { float f; unsigned u; } x; x.f = f;
  unsigned r = x.u + 0x7FFFu + ((x.u >> 16) & 1u);  // RNE
  return (bfu)(r >> 16);
}
__device__ __forceinline__ float fsig(float x) {
  return __builtin_amdgcn_rcpf(1.f + __expf(-x));
}
__device__ __forceinline__ float fsilu(float x) { return x * fsig(x); }

// ---- 8-wide (16B/lane) row math over 32-lane groups ----
struct f8 { float v[8]; };
__device__ __forceinline__ f8 ld8(const bfu* p) {
  short8 u = *(const short8*)(const void*)p;
  f8 r;
#pragma unroll
  for (int i = 0; i < 8; ++i) r.v[i] = bf2f((bfu)u[i]);
  return r;
}
__device__ __forceinline__ void st8(bfu* p, f8 x) {
  short8 u;
#pragma unroll
  for (int i = 0; i < 8; ++i) u[i] = (short)f2bf(x.v[i]);
  *(short8*)(void*)p = u;
}
__device__ __forceinline__ f8 add8(f8 a, f8 b) {
  f8 r;
#pragma unroll
  for (int i = 0; i < 8; ++i) r.v[i] = a.v[i] + b.v[i];
  return r;
}
__device__ __forceinline__ f8 sig8(f8 m) {
  f8 r;
#pragma unroll
  for (int i = 0; i < 8; ++i) r.v[i] = fsig(m.v[i]);
  return r;
}
__device__ __forceinline__ void wstats32(const f8& x, float& mean, float& rstd) {
  float s = 0.f, q = 0.f;
#pragma unroll
  for (int i = 0; i < 8; ++i) { s += x.v[i]; q += x.v[i] * x.v[i]; }
#pragma unroll
  for (int m = 1; m < 32; m <<= 1) { s += __shfl_xor(s, m); q += __shfl_xor(q, m); }
  mean = s * (1.f / 256.f);
  rstd = rsqrtf(fmaxf(q * (1.f / 256.f) - mean * mean, 0.f) + 1e-5f);
}
__device__ __forceinline__ f8 lnsilu8(f8 pre, f8 sg, f8 bb) {
  float mean, rstd; wstats32(pre, mean, rstd);
  f8 r;
#pragma unroll
  for (int i = 0; i < 8; ++i)
    r.v[i] = fsilu((pre.v[i] - mean) * rstd * sg.v[i] + bb.v[i]);
  return r;
}

__device__ __forceinline__ float block_sum256(float t, float* sm) {
#pragma unroll
  for (int o = 32; o; o >>= 1) t += __shfl_down(t, o);
  if ((threadIdx.x & 63) == 0) sm[threadIdx.x >> 6] = t;
  __syncthreads();
  float r = sm[0] + sm[1] + sm[2] + sm[3];
  __syncthreads();
  return r;
}

// ------------------------------------------------------- dtype handling ----
__global__ void probe_kernel(const unsigned* __restrict__ ones_raw, int* __restrict__ mode) {
  if (threadIdx.x == 0) *mode = (ones_raw[0] == 0x3F800000u) ? 1 : 0;
}
__global__ __launch_bounds__(256) void cvt_kernel(
    const void* __restrict__ src, bfu* __restrict__ dst, int n, const int* __restrict__ mode) {
  int i = blockIdx.x * 256 + threadIdx.x;
  if (i >= n) return;
  dst[i] = (*mode) ? f2bf(((const float*)src)[i]) : ((const bfu*)src)[i];
}
__global__ __launch_bounds__(256) void cvtf_kernel(
    const void* __restrict__ src, float* __restrict__ dst, int n, const int* __restrict__ mode) {
  int i = blockIdx.x * 256 + threadIdx.x;
  if (i >= n) return;
  dst[i] = (*mode) ? ((const float*)src)[i] : bf2f(((const bfu*)src)[i]);
}
struct CvtDesc { const void* src; bfu* dst; int n; };
struct CvtPack { CvtDesc e[20]; };
__global__ __launch_bounds__(256) void cvt_batch_kernel(CvtPack p, const int* __restrict__ mode) {
  CvtDesc d = p.e[blockIdx.y];
  int i = blockIdx.x * 256 + threadIdx.x;
  if (i >= d.n) return;
  d.dst[i] = (*mode) ? f2bf(((const float*)d.src)[i]) : ((const bfu*)d.src)[i];
}

// ---------------------------------------------------------------- GEMM ----
template<int BM, int BN, int WR, int WC>
__device__ __forceinline__ void gemm_body(
    const bfu* __restrict__ A, const bfu* __restrict__ Bt,
    const bfu* __restrict__ bias, bfu* __restrict__ Cout,
    int cnt, int N, int K, int base, int m0, int n0)
{
  constexpr int WM = BM / WR, WN = BN / WC;
  constexpr int TM = WM / 16, TN = WN / 16;
  constexpr int LDT = 72;
  static __shared__ bfu As[BM * LDT];
  static __shared__ bfu Bs[BN * LDT];

  const int tid = threadIdx.x, wave = tid >> 6, lane = tid & 63;
  const int wr = wave / WC, wc = wave % WC;
  const int lrow = lane & 15, kq = (lane >> 4) * 8;

  floatx4 acc[TM][TN];
#pragma unroll
  for (int i = 0; i < TM; ++i)
#pragma unroll
    for (int j = 0; j < TN; ++j) acc[i][j] = (floatx4){0.f, 0.f, 0.f, 0.f};

  constexpr int ACH = BM * 8, BCH = BN * 8;
  for (int k0 = 0; k0 < K; k0 += 64) {
#pragma unroll
    for (int idx = tid; idx < ACH; idx += 256) {
      int row = idx >> 3, kc = (idx & 7) << 3;
      int r = m0 + row;
      int ar = base + (r < cnt ? r : cnt - 1);
      *(short8*)(void*)(As + row * LDT + kc) =
          *(const short8*)(const void*)(A + (size_t)ar * K + k0 + kc);
    }
#pragma unroll
    for (int idx = tid; idx < BCH; idx += 256) {
      int row = idx >> 3, kc = (idx & 7) << 3;
      *(short8*)(void*)(Bs + row * LDT + kc) =
          *(const short8*)(const void*)(Bt + (size_t)(n0 + row) * K + k0 + kc);
    }
    __syncthreads();
#pragma unroll
    for (int s = 0; s < 2; ++s) {
      short8 Af[TM], Bf[TN];
#pragma unroll
      for (int i = 0; i < TM; ++i)
        Af[i] = *(const short8*)(const void*)(As + (wr * WM + i * 16 + lrow) * LDT + s * 32 + kq);
#pragma unroll
      for (int j = 0; j < TN; ++j)
        Bf[j] = *(const short8*)(const void*)(Bs + (wc * WN + j * 16 + lrow) * LDT + s * 32 + kq);
#pragma unroll
      for (int i = 0; i < TM; ++i)
#pragma unroll
        for (int j = 0; j < TN; ++j)
          acc[i][j] = __builtin_amdgcn_mfma_f32_16x16x32_bf16(Af[i], Bf[j], acc[i][j], 0, 0, 0);
    }
    __syncthreads();
  }

  const int rquad = lane >> 4, cin = lane & 15;
#pragma unroll
  for (int i = 0; i < TM; ++i) {
#pragma unroll
    for (int rr = 0; rr < 4; ++rr) {
      int orow = m0 + wr * WM + i * 16 + rquad * 4 + rr;
      if (orow >= cnt) continue;
#pragma unroll
      for (int j = 0; j < TN; ++j) {
        int gcol = n0 + wc * WN + j * 16 + cin;
        Cout[(size_t)orow * N + gcol] = f2bf(acc[i][j][rr] + bf2f(bias[gcol]));
      }
    }
  }
}

template<int BM, int BN, int WR, int WC>
__global__ __launch_bounds__(256) void gemm_kernel(
    const bfu* __restrict__ A, const bfu* __restrict__ Bt,
    const bfu* __restrict__ bias, bfu* __restrict__ Cout, int M, int N, int K)
{
  gemm_body<BM, BN, WR, WC>(A, Bt, bias, Cout, M, N, K, 0,
                            blockIdx.x * BM, blockIdx.y * BN);
}

// merged atom gates + m launch: grid (512, 2)
__global__ __launch_bounds__(256) void atom_gemm_kernel(
    const bfu* __restrict__ x, const bfu* __restrict__ y,
    const bfu* __restrict__ W, const bfu* __restrict__ bb,
    bfu* __restrict__ afused, bfu* __restrict__ mbufa)
{
  if (blockIdx.x < 384) {
    gemm_body<128, 128, 2, 2>(y, W + 4 * HH, bb + 4 * 256, mbufa,
                              49152, 256, 256, 0, blockIdx.x * 128, blockIdx.y * 128);
  } else {
    int lid = (blockIdx.x - 384) * 2 + blockIdx.y;  // 0..255
    gemm_body<128, 128, 2, 2>(x, W, bb, afused,
                              4096, 1024, 256, 0, (lid >> 3) * 128, (lid & 7) * 128);
  }
}

// merged line gates + chunk-0 m/u3 GEMM: grid (384, 9)
__global__ __launch_bounds__(256) void line_gates_kernel(
    const bfu* __restrict__ y, const bfu* __restrict__ z,
    const bfu* __restrict__ W, const bfu* __restrict__ bb,
    bfu* __restrict__ lfused, bfu* __restrict__ mch0, bfu* __restrict__ u3c0,
    const int* __restrict__ loff)
{
  if (blockIdx.y < 6) {
    gemm_body<128, 128, 2, 2>(y, W, bb, lfused,
                              49152, 768, 256, 0, blockIdx.x * 128, blockIdx.y * 128);
  } else if (blockIdx.y < 8) {
    int cnt = loff[CHN];
    int m0 = blockIdx.x * 128;
    if (blockIdx.x >= CHCAP / 128 || m0 >= cnt) return;
    gemm_body<128, 128, 2, 2>(z, W + 4 * HH, bb + 4 * 256, mch0,
                              cnt, 256, 256, 0, m0, (blockIdx.y - 6) * 128);
  } else {
    if (blockIdx.x >= 32) return;
    gemm_body<128, 128, 2, 2>(y, W + 3 * HH, bb + 3 * 256, u3c0,
                              CHN, 256, 256, 0, (blockIdx.x & 15) * 128, (blockIdx.x >> 4) * 128);
  }
}

// ---------------------- pipelined line step: fused(c) + GEMM(c+1) ----------
// blocks [0,eblk): edge update chunk c; [eblk, eblk+CHN/4): node agg chunk c;
// rest: m-GEMM + u3-GEMM for chunk c+1 into the B buffers.
__global__ __launch_bounds__(256) void line_step_kernel(
    const bfu* __restrict__ z, const bfu* __restrict__ yb,
    const bfu* __restrict__ lf, const bfu* __restrict__ W, const bfu* __restrict__ bb,
    const bfu* __restrict__ mA, bfu* __restrict__ mB,
    const bfu* __restrict__ u3A, bfu* __restrict__ u3B,
    const int* __restrict__ loff, const int* __restrict__ lsrc_p,
    const int* __restrict__ ldst_p,
    bfu* __restrict__ Z, bfu* __restrict__ Y,
    int n0, int eblk, int do_gemm,
    const bfu* __restrict__ lns, const bfu* __restrict__ lnb,
    const bfu* __restrict__ les, const bfu* __restrict__ leb)
{
  const int nblk = CHN / 4;
  int bx = blockIdx.x;
  if (bx < eblk + nblk) {
    int wave = threadIdx.x >> 6, lane = threadIdx.x & 63;
    int half = lane >> 5, c8 = (lane & 31) * 8;
    int base = loff[n0];
    if (bx < eblk) {
      int rloc = bx * 8 + wave * 2 + half;
      int cnt = loff[n0 + CHN] - base;
      if (rloc >= cnt) return;
      int p = base + rloc;
      f8 m = add8(add8(ld8(mA + (size_t)rloc * 256 + c8),
                       ld8(lf + (size_t)lsrc_p[p] * 768 + c8)),
                  ld8(lf + (size_t)ldst_p[p] * 768 + 512 + c8));
      f8 sil = lnsilu8(m, ld8(les + c8), ld8(leb + c8));
      bfu* op = Z + (size_t)p * 256 + c8;
      st8(op, add8(sil, ld8(op)));
    } else {
      int n = n0 + (bx - eblk) * 4 + wave;
      int p0 = loff[n], p1 = loff[n + 1];
      f8 g1 = ld8(lf + (size_t)n * 768 + 512 + c8);
      f8 num = {}, den = {};
      for (int p = p0 + half; p < p1; p += 2) {
        int sx = lsrc_p[p];
        f8 m = add8(add8(ld8(mA + (size_t)(p - base) * 256 + c8),
                         ld8(lf + (size_t)sx * 768 + c8)), g1);
        f8 sg = sig8(m);
        f8 u4 = ld8(lf + (size_t)sx * 768 + 256 + c8);
#pragma unroll
        for (int i = 0; i < 8; ++i) {
          num.v[i] += sg.v[i] * u4.v[i];
          den.v[i] += sg.v[i];
        }
      }
#pragma unroll
      for (int i = 0; i < 8; ++i) {
        num.v[i] += __shfl_xor(num.v[i], 32);
        den.v[i] += __shfl_xor(den.v[i], 32);
      }
      f8 u3 = ld8(u3A + (size_t)(n - n0) * 256 + c8);
      f8 pre;
#pragma unroll
      for (int i = 0; i < 8; ++i)
        pre.v[i] = u3.v[i] + num.v[i] / (den.v[i] + 1e-6f);
      f8 sil = lnsilu8(pre, ld8(lns + c8), ld8(lnb + c8));
      if (half == 0) {
        bfu* op = Y + (size_t)n * 256 + c8;
        st8(op, add8(sil, ld8(op)));
      }
    }
  } else {
    if (!do_gemm) return;
    int gb = bx - (eblk + nblk);
    int n1 = n0 + CHN;
    if (gb < (CHCAP / 128) * 2) {
      int base = loff[n1], cnt = loff[n1 + CHN] - base;
      int m0 = (gb >> 1) * 128;
      if (m0 >= cnt) return;
      gemm_body<128, 128, 2, 2>(z, W + 4 * HH, bb + 4 * 256, mB,
                                cnt, 256, 256, base, m0, (gb & 1) * 128);
    } else {
      int ub = gb - (CHCAP / 128) * 2;   // 0..31
      gemm_body<128, 128, 2, 2>(yb + (size_t)n1 * 256, W + 3 * HH, bb + 3 * 256, u3B,
                                CHN, 256, 256, 0, (ub & 15) * 128, (ub >> 4) * 128);
    }
  }
}

// --------------------------------------------- cos / bondlength precompute ----
__global__ __launch_bounds__(256) void cosbl_kernel(
    const float* __restrict__ r, const int* __restrict__ lsrc_p,
    const int* __restrict__ ldst_p, float* __restrict__ cosv,
    float* __restrict__ bl, int T, int E)
{
  int idx = blockIdx.x * 256 + threadIdx.x;
  if (idx < T) {
    int e1 = lsrc_p[idx], e2 = ldst_p[idx];
    float ax = -r[e1 * 3 + 0], ay = -r[e1 * 3 + 1], az = -r[e1 * 3 + 2];
    float bx =  r[e2 * 3 + 0], by =  r[e2 * 3 + 1], bz =  r[e2 * 3 + 2];
    float dot = ax * bx + ay * by + az * bz;
    float na = sqrtf(ax * ax + ay * ay + az * az);
    float nb = sqrtf(bx * bx + by * by + bz * bz);
    float c = dot / (na * nb);
    cosv[idx] = fminf(1.f, fmaxf(-1.f, c));
  } else if (idx < T + E) {
    int e = idx - T;
    float x = r[e * 3 + 0], yv = r[e * 3 + 1], zv = r[e * 3 + 2];
    bl[e] = sqrtf(x * x + yv * yv + zv * zv);
  }
}

// ------------------------- MLP1 fused: rbf(in staging) @ W1 + b1 -> LN64+SiLU
template<int KP, int BINS, int IS_ANG>
__global__ __launch_bounds__(256) void mlp1_ln_kernel(
    const float* __restrict__ v, const bfu* __restrict__ Bt,
    const bfu* __restrict__ bias, const bfu* __restrict__ lns,
    const bfu* __restrict__ lnb, bfu* __restrict__ outp, int M)
{
  constexpr int LDT = KP + 8;
  __shared__ bfu As[128 * LDT];
  const int tid = threadIdx.x, wave = tid >> 6, lane = tid & 63;
  const int lrow = lane & 15, kq = (lane >> 4) * 8;
  const int m0 = blockIdx.x * 128;

  for (int idx = tid; idx < 128 * (KP / 8); idx += 256) {
    int row = idx / (KP / 8), kc = (idx % (KP / 8)) * 8;
    float val = v[m0 + row];
    short8 pack;
#pragma unroll
    for (int jj = 0; jj < 8; ++jj) {
      int k = kc + jj;
      float e = 0.f;
      if (k < BINS) {
        float center = IS_ANG ? (-1.f + k * (2.f / 39.f)) : (k * (8.f / 79.f));
        float d = val - center;
        e = __expf((IS_ANG ? -19.5f : -9.875f) * d * d);
      }
      pack[jj] = (short)f2bf(e);
    }
    *(short8*)(void*)(As + row * LDT + kc) = pack;
  }
  __syncthreads();

  floatx4 acc[2][4];
#pragma unroll
  for (int i = 0; i < 2; ++i)
#pragma unroll
    for (int j = 0; j < 4; ++j) acc[i][j] = (floatx4){0.f, 0.f, 0.f, 0.f};
#pragma unroll
  for (int ks = 0; ks < KP / 32; ++ks) {
    short8 Af[2], Bf[4];
#pragma unroll
    for (int j = 0; j < 4; ++j)
      Bf[j] = *(const short8*)(const void*)(Bt + (size_t)(j * 16 + lrow) * KP + ks * 32 + kq);
#pragma unroll
    for (int i = 0; i < 2; ++i)
      Af[i] = *(const short8*)(const void*)(As + (wave * 32 + i * 16 + lrow) * LDT + ks * 32 + kq);
#pragma unroll
    for (int i = 0; i < 2; ++i)
#pragma unroll
      for (int j = 0; j < 4; ++j)
        acc[i][j] = __builtin_amdgcn_mfma_f32_16x16x32_bf16(Af[i], Bf[j], acc[i][j], 0, 0, 0);
  }

  const int rquad = lane >> 4, cin = lane & 15;
  float bj[4], sj[4], lj[4];
#pragma unroll
  for (int j = 0; j < 4; ++j) {
    bj[j] = bf2f(bias[j * 16 + cin]);
    sj[j] = bf2f(lns[j * 16 + cin]);
    lj[j] = bf2f(lnb[j * 16 + cin]);
  }
#pragma unroll
  for (int i = 0; i < 2; ++i) {
#pragma unroll
    for (int rr = 0; rr < 4; ++rr) {
      int row = m0 + wave * 32 + i * 16 + rquad * 4 + rr;
      float pre[4], s = 0.f, q = 0.f;
#pragma unroll
      for (int j = 0; j < 4; ++j) {
        pre[j] = acc[i][j][rr] + bj[j];
        s += pre[j]; q += pre[j] * pre[j];
      }
#pragma unroll
      for (int mm = 1; mm < 16; mm <<= 1) { s += __shfl_xor(s, mm); q += __shfl_xor(q, mm); }
      float mean = s * (1.f / 64.f);
      float rstd = rsqrtf(fmaxf(q * (1.f / 64.f) - mean * mean, 0.f) + 1e-5f);
#pragma unroll
      for (int j = 0; j < 4; ++j) {
        float u = (pre[j] - mean) * rstd * sj[j] + lj[j];
        outp[(size_t)row * 64 + j * 16 + cin] = f2bf(fsilu(u));
      }
    }
  }
}

// ------------- MLP2 fused: emb[M,64] @ W2 + b2 -> LN256+SiLU -> out[M,256]
__global__ __launch_bounds__(256) void mlp2_ln_kernel(
    const bfu* __restrict__ A, const bfu* __restrict__ Bt,
    const bfu* __restrict__ bias, const bfu* __restrict__ lns,
    const bfu* __restrict__ lnb, bfu* __restrict__ outp, int M)
{
  __shared__ bfu As[64 * 72];
  __shared__ float part[64 * 8];
  const int tid = threadIdx.x, wave = tid >> 6, lane = tid & 63;
  const int lrow = lane & 15, kq = (lane >> 4) * 8;
  const int m0 = blockIdx.x * 64;

  short8 Bf[2][4];
#pragma unroll
  for (int s = 0; s < 2; ++s)
#pragma unroll
    for (int j = 0; j < 4; ++j)
      Bf[s][j] = *(const short8*)(const void*)(
          Bt + (size_t)(wave * 64 + j * 16 + lrow) * 64 + s * 32 + kq);

  for (int idx = tid; idx < 512; idx += 256) {
    int row = idx >> 3, kc = (idx & 7) << 3;
    *(short8*)(void*)(As + row * 72 + kc) =
        *(const short8*)(const void*)(A + (size_t)(m0 + row) * 64 + kc);
  }
  __syncthreads();

  floatx4 acc[4][4];
#pragma unroll
  for (int i = 0; i < 4; ++i)
#pragma unroll
    for (int j = 0; j < 4; ++j) acc[i][j] = (floatx4){0.f, 0.f, 0.f, 0.f};
#pragma unroll
  for (int s = 0; s < 2; ++s) {
    short8 Af[4];
#pragma unroll
    for (int i = 0; i < 4; ++i)
      Af[i] = *(const short8*)(const void*)(As + (i * 16 + lrow) * 72 + s * 32 + kq);
#pragma unroll
    for (int i = 0; i < 4; ++i)
#pragma unroll
      for (int j = 0; j < 4; ++j)
        acc[i][j] = __builtin_amdgcn_mfma_f32_16x16x32_bf16(Af[i], Bf[s][j], acc[i][j], 0, 0, 0);
  }

  const int rquad = lane >> 4, cin = lane & 15;
  float bj[4], sj[4], lj[4];
#pragma unroll
  for (int j = 0; j < 4; ++j) {
    int col = wave * 64 + j * 16 + cin;
    bj[j] = bf2f(bias[col]); sj[j] = bf2f(lns[col]); lj[j] = bf2f(lnb[col]);
  }
#pragma unroll
  for (int i = 0; i < 4; ++i) {
#pragma unroll
    for (int rr = 0; rr < 4; ++rr) {
      float s = 0.f, q = 0.f;
#pragma unroll
      for (int j = 0; j < 4; ++j) {
        float p = acc[i][j][rr] + bj[j];
        s += p; q += p * p;
      }
#pragma unroll
      for (int mm = 1; mm < 16; mm <<= 1) { s += __shfl_xor(s, mm); q += __shfl_xor(q, mm); }
      if (cin == 0) {
        int row = i * 16 + rquad * 4 + rr;
        part[row * 8 + wave * 2] = s;
        part[row * 8 + wave * 2 + 1] = q;
      }
    }
  }
  __syncthreads();
#pragma unroll
  for (int i = 0; i < 4; ++i) {
#pragma unroll
    for (int rr = 0; rr < 4; ++rr) {
      int row = i * 16 + rquad * 4 + rr;
      float s = part[row * 8] + part[row * 8 + 2] + part[row * 8 + 4] + part[row * 8 + 6];
      float q = part[row * 8 + 1] + part[row * 8 + 3] + part[row * 8 + 5] + part[row * 8 + 7];
      float mean = s * (1.f / 256.f);
      float rstd = rsqrtf(fmaxf(q * (1.f / 256.f) - mean * mean, 0.f) + 1e-5f);
#pragma unroll
      for (int j = 0; j < 4; ++j) {
        float u = (acc[i][j][rr] + bj[j] - mean) * rstd * sj[j] + lj[j];
        outp[(size_t)(m0 + row) * 256 + wave * 64 + j * 16 + cin] = f2bf(fsilu(u));
      }
    }
  }
}

// ----------------------------------------------------------- CSR build ----
__global__ __launch_bounds__(256) void count_kernel(
    const int* __restrict__ d, int* __restrict__ cnt, int ne) {
  int i = blockIdx.x * 256 + threadIdx.x;
  if (i < ne) atomicAdd(&cnt[d[i]], 1);
}
__global__ __launch_bounds__(256) void scan_kernel(
    const int* __restrict__ cnt, int* __restrict__ off, int n) {
  __shared__ int ssum[256];
  __shared__ int sbase[257];
  int t = threadIdx.x;
  int strip = (n + 255) / 256;
  int lo = t * strip, hi = lo + strip; if (hi > n) hi = n; if (lo > n) lo = n;
  int s = 0;
  for (int i = lo; i < hi; ++i) s += cnt[i];
  ssum[t] = s;
  __syncthreads();
  if (t == 0) {
    int run = 0;
    for (int i = 0; i < 256; ++i) { sbase[i] = run; run += ssum[i]; }
    sbase[256] = run;
  }
  __syncthreads();
  int run = sbase[t];
  for (int i = lo; i < hi; ++i) { off[i] = run; run += cnt[i]; }
  if (t == 0) off[n] = sbase[256];
}
__global__ __launch_bounds__(256) void copy_kernel(
    const int* __restrict__ a, int* __restrict__ b, int n) {
  int i = blockIdx.x * 256 + threadIdx.x;
  if (i < n) b[i] = a[i];
}
__global__ __launch_bounds__(256) void fill_kernel(
    const int* __restrict__ d, int* __restrict__ cur, int* __restrict__ ids, int ne) {
  int i = blockIdx.x * 256 + threadIdx.x;
  if (i < ne) ids[atomicAdd(&cur[d[i]], 1)] = i;
}
__global__ __launch_bounds__(256) void fill2_kernel(
    const int* __restrict__ ldst, const int* __restrict__ lsrc, int* __restrict__ cur,
    int* __restrict__ lsrc_p, int* __restrict__ ldst_p, int ne) {
  int i = blockIdx.x * 256 + threadIdx.x;
  if (i >= ne) return;
  int d = ldst[i];
  int pos = atomicAdd(&cur[d], 1);
  lsrc_p[pos] = lsrc[i];
  ldst_p[pos] = d;
}

// ------------------------------------------------------ weight transpose ----
__global__ __launch_bounds__(256) void transpose_pad_kernel(
    const void* __restrict__ W, bfu* __restrict__ Wt, int K, int N, int Kp,
    const int* __restrict__ mode)
{
  int idx = blockIdx.x * 256 + threadIdx.x;
  if (idx >= N * Kp) return;
  int n = idx / Kp, k = idx - n * Kp;
  bfu v = 0;
  if (k < K) {
    size_t si = (size_t)k * N + n;
    v = (*mode) ? f2bf(((const float*)W)[si]) : ((const bfu*)W)[si];
  }
  Wt[idx] = v;
}
// unified slot order: [W0, W4, W1, W3, W2] -> gates [g0|u4|g1(|u3)], m slot 4
__device__ __forceinline__ int slot2mat(int slot) {
  const int m[5] = {0, 4, 1, 3, 2};
  return m[slot];
}
__global__ __launch_bounds__(256) void transpose_eggc_kernel(
    const void* __restrict__ W, bfu* __restrict__ Wt, const int* __restrict__ mode)
{
  int bs = blockIdx.y;
  int blk = bs / 5, slot = bs - blk * 5;
  int mat = slot2mat(slot);
  int idx = blockIdx.x * 256 + threadIdx.x;
  int n = idx >> 8, k = idx & 255;
  size_t si = ((size_t)(blk * 5 + mat) * 256 + k) * 256 + n;
  bfu v = (*mode) ? f2bf(((const float*)W)[si]) : ((const bfu*)W)[si];
  Wt[((size_t)bs * 256 + n) * 256 + k] = v;
}
__global__ __launch_bounds__(256) void bias_perm_kernel(
    const void* __restrict__ B, bfu* __restrict__ Bp, const int* __restrict__ mode)
{
  int i = blockIdx.x * 256 + threadIdx.x;
  int bs = i >> 8, c = i & 255;
  int blk = bs / 5, slot = bs - blk * 5;
  int mat = slot2mat(slot);
  size_t si = (size_t)(blk * 5 + mat) * 256 + c;
  Bp[i] = (*mode) ? f2bf(((const float*)B)[si]) : ((const bfu*)B)[si];
}

// -------------------------------------------------- atom fused edge+agg ----
__global__ __launch_bounds__(256) void atom_fused_kernel(
    const bfu* __restrict__ mbuf, const bfu* __restrict__ af,
    const int* __restrict__ src, const int* __restrict__ dst,
    bfu* __restrict__ X, bfu* __restrict__ Y,
    const int* __restrict__ aoff, const int* __restrict__ aids,
    int eblk,
    const bfu* __restrict__ lns, const bfu* __restrict__ lnb,
    const bfu* __restrict__ les, const bfu* __restrict__ leb)
{
  int wave = threadIdx.x >> 6, lane = threadIdx.x & 63;
  int half = lane >> 5, c8 = (lane & 31) * 8;
  if ((int)blockIdx.x < eblk) {
    int e = blockIdx.x * 8 + wave * 2 + half;
    f8 m = add8(add8(ld8(mbuf + (size_t)e * 256 + c8),
                     ld8(af + (size_t)src[e] * 1024 + c8)),
                ld8(af + (size_t)dst[e] * 1024 + 512 + c8));
    f8 sil = lnsilu8(m, ld8(les + c8), ld8(leb + c8));
    bfu* op = Y + (size_t)e * 256 + c8;
    st8(op, add8(sil, ld8(op)));
  } else {
    int n = (blockIdx.x - eblk) * 4 + wave;
    int p0 = aoff[n], p1 = aoff[n + 1];
    f8 g1 = ld8(af + (size_t)n * 1024 + 512 + c8);
    f8 num = {}, den = {};
    for (int p = p0 + half; p < p1; p += 2) {
      int id = aids[p], sx = src[id];
      f8 m = add8(add8(ld8(mbuf + (size_t)id * 256 + c8),
                       ld8(af + (size_t)sx * 1024 + c8)), g1);
      f8 sg = sig8(m);
      f8 u4 = ld8(af + (size_t)sx * 1024 + 256 + c8);
#pragma unroll
      for (int i = 0; i < 8; ++i) {
        num.v[i] += sg.v[i] * u4.v[i];
        den.v[i] += sg.v[i];
      }
    }
#pragma unroll
    for (int i = 0; i < 8; ++i) {
      num.v[i] += __shfl_xor(num.v[i], 32);
      den.v[i] += __shfl_xor(den.v[i], 32);
    }
    f8 u3 = ld8(af + (size_t)n * 1024 + 768 + c8);
    f8 pre;
#pragma unroll
    for (int i = 0; i < 8; ++i)
      pre.v[i] = u3.v[i] + num.v[i] / (den.v[i] + 1e-6f);
    f8 sil = lnsilu8(pre, ld8(lns + c8), ld8(lnb + c8));
    if (half == 0) {
      bfu* op = X + (size_t)n * 256 + c8;
      st8(op, add8(sil, ld8(op)));
    }
  }
}

// ----------------------------------------------------------- atom init ----
__global__ __launch_bounds__(256) void atom_init_kernel(
    const bfu* __restrict__ af, const bfu* __restrict__ W, const bfu* __restrict__ bias,
    const bfu* __restrict__ lns, const bfu* __restrict__ lnb, bfu* __restrict__ X)
{
  __shared__ float sm[4];
  int row = blockIdx.x, c = threadIdx.x;
  float acc = bf2f(bias[c]);
  for (int k = 0; k < 92; ++k)
    acc += bf2f(af[row * 92 + k]) * bf2f(W[k * 256 + c]);
  float mean = block_sum256(acc, sm) * (1.f / 256.f);
  float d = acc - mean;
  float var = block_sum256(d * d, sm) * (1.f / 256.f);
  float u = d * rsqrtf(var + 1e-5f) * bf2f(lns[c]) + bf2f(lnb[c]);
  X[(size_t)row * 256 + c] = f2bf(fsilu(u));
}

// --------------------------------------------------------------- final ----
__global__ __launch_bounds__(256) void final_kernel(
    const bfu* __restrict__ X, const bfu* __restrict__ fcW, const bfu* __restrict__ fcb,
    void* __restrict__ out, float* __restrict__ acc, const int* __restrict__ mode)
{
  int row = blockIdx.x * 4 + (threadIdx.x >> 6);
  int lane = threadIdx.x & 63;
  float s = 0.f;
#pragma unroll
  for (int k = 0; k < 4; ++k)
    s += bf2f(X[(size_t)row * 256 + lane + k * 64]) * bf2f(fcW[lane + k * 64]);
#pragma unroll
  for (int o = 32; o; o >>= 1) s += __shfl_down(s, o);
  if (lane == 0) {
    float v = s + bf2f(fcb[0]);
    if (*mode) ((float*)out)[1 + row] = v;
    else       ((bfu*)out)[1 + row] = f2bf(v);
    atomicAdd(acc, v);
  }
}
__global__ void mean_kernel(const float* __restrict__ acc, void* __restrict__ out,
                            const int* __restrict__ mode) {
  if (threadIdx.x == 0) {
    float v = acc[0] * (1.f / 4096.f);
    if (*mode) ((float*)out)[0] = v;
    else       ((bfu*)out)[0] = f2bf(v);
  }
}
__global__ void dbg_kernel(void* __restrict__ out, float v) {
  if (threadIdx.x == 0) { ((bfu*)out)[0] = f2bf(v); }
}

// ---------------------------------------------------------------- host ----
static void gemm128(const bfu* A, const bfu* Bt, const bfu* bias, bfu* C,
                    int M, int N, int K, hipStream_t st) {
  dim3 g(M / 128, N / 128);
  gemm_kernel<128, 128, 2, 2><<<g, 256, 0, st>>>(A, Bt, bias, C, M, N, K);
}

extern "C" void kernel_launch(void* const* d_in, const int* in_sizes, int n_in,
                              void* d_out, int out_size, void* d_ws, size_t ws_size,
                              hipStream_t stream) {
  const int N = 4096, E = 49152, T = 262144, H = 256;

  const int* src  = (const int*)d_in[2];
  const int* dst  = (const int*)d_in[3];
  const int* lsrc = (const int*)d_in[4];
  const int* ldst = (const int*)d_in[5];

  // ---- workspace carve (~262 MB, proven fit) ----
  char* bp = (char*)d_ws;
  size_t off = 0;
  auto carve = [&](size_t bytes) -> char* {
    char* q = bp + off;
    off = (off + bytes + 255) & ~(size_t)255;
    return q;
  };
  bfu* x       = (bfu*)carve((size_t)N * H * 2);
  bfu* y       = (bfu*)carve((size_t)E * H * 2);
  bfu* z       = (bfu*)carve((size_t)T * H * 2);       // ldst-sorted
  bfu* reg     = (bfu*)carve((size_t)E * 768 * 2);
  bfu* u3c     = (bfu*)carve((size_t)2 * CHN * H * 2);    // double-buffered
  bfu* mchunk  = (bfu*)carve((size_t)2 * CHCAP * H * 2);  // double-buffered
  bfu* WtE     = (bfu*)carve((size_t)60 * H * H * 2);  // slot-ordered
  bfu* ebp     = (bfu*)carve((size_t)12 * 5 * H * 2);
  bfu* Wt_a1   = (bfu*)carve(64 * 64 * 2);
  bfu* Wt_a2   = (bfu*)carve(256 * 64 * 2);
  bfu* Wt_e1   = (bfu*)carve(64 * 128 * 2);
  bfu* Wt_e2   = (bfu*)carve(256 * 64 * 2);
  int* aoff    = (int*)carve((size_t)(N + 1) * 4);
  int* aids    = (int*)carve((size_t)E * 4);
  int* loff    = (int*)carve((size_t)(E + 1) * 4);
  int* lsrc_p  = (int*)carve((size_t)T * 4);
  int* ldst_p  = (int*)carve((size_t)T * 4);
  int* cursors = (int*)carve((size_t)E * 4);
  float* macc  = (float*)carve(256);
  int* mode    = (int*)carve(256);
  bfu* par_c   = (bfu*)carve(8192 * 2);
  bfu* els_c   = (bfu*)carve((size_t)12 * 2 * H * 2);
  bfu* elb_c   = (bfu*)carve((size_t)12 * 2 * H * 2);

  if (off > ws_size) {
    hipMemsetAsync(d_out, 0, (size_t)out_size * 2, stream);
    dbg_kernel<<<1, 64, 0, stream>>>(d_out, (float)(ws_size >> 20));
    return;
  }

  // early-phase scratch in reg tail
  char* tail = (char*)reg + (size_t)52 * 1024 * 1024;
  bfu* af_c  = (bfu*)tail;                 tail += ((size_t)N * 92 * 2 + 255) & ~255ull;
  float* r_f = (float*)tail;               tail += ((size_t)E * 3 * 4 + 255) & ~255ull;
  float* cosv = (float*)tail;              tail += ((size_t)T * 4 + 255) & ~255ull;
  float* blv = (float*)tail;               tail += ((size_t)E * 4 + 255) & ~255ull;
  bfu* atW_c = (bfu*)tail;

  // packed small params
  bfu* atom_b_c   = par_c + 0;
  bfu* atom_lns_c = par_c + 256;
  bfu* atom_lnb_c = par_c + 512;
  bfu* e_b1_c     = par_c + 768;
  bfu* e_l1s_c    = par_c + 832;
  bfu* e_l1b_c    = par_c + 896;
  bfu* e_b2_c     = par_c + 1024;
  bfu* e_l2s_c    = par_c + 1280;
  bfu* e_l2b_c    = par_c + 1536;
  bfu* a_b1_c     = par_c + 1792;
  bfu* a_l1s_c    = par_c + 1856;
  bfu* a_l1b_c    = par_c + 1920;
  bfu* a_b2_c     = par_c + 2048;
  bfu* a_l2s_c    = par_c + 2304;
  bfu* a_l2b_c    = par_c + 2560;
  bfu* fcW_c      = par_c + 2816;
  bfu* fcb_c      = par_c + 3072;

  // overlays within reg
  bfu* lfused = reg;                        // line: [E,768] g0|u4|g1
  bfu* afused = reg;                        // atom: [N,1024] g0|u4|g1|u3
  bfu* mbufa  = reg + (size_t)N * 1024;     // atom: [E,256] m_raw
  bfu* emb_t  = reg;                        // early: [T,64]
  bfu* emb_e  = reg + (size_t)T * 64;       // early: [E,64]

  // ---- dtype probe + param conversion ----
  probe_kernel<<<1, 64, 0, stream>>>((const unsigned*)d_in[8], mode);
  CvtPack pk;
  int ii = 0;
  auto add = [&](int idx, bfu* dstp, int n) { pk.e[ii++] = {d_in[idx], dstp, n}; };
  add(7, atom_b_c, 256);  add(8, atom_lns_c, 256); add(9, atom_lnb_c, 256);
  add(11, e_b1_c, 64);    add(12, e_l1s_c, 64);    add(13, e_l1b_c, 64);
  add(15, e_b2_c, 256);   add(16, e_l2s_c, 256);   add(17, e_l2b_c, 256);
  add(19, a_b1_c, 64);    add(20, a_l1s_c, 64);    add(21, a_l1b_c, 64);
  add(23, a_b2_c, 256);   add(24, a_l2s_c, 256);   add(25, a_l2b_c, 256);
  add(30, fcW_c, 256);    add(31, fcb_c, 1);
  add(28, els_c, 12 * 2 * 256);
  add(29, elb_c, 12 * 2 * 256);
  add(6, atW_c, 92 * 256);
  cvt_batch_kernel<<<dim3(92, 20), 256, 0, stream>>>(pk, mode);
  cvt_kernel<<<(N * 92 + 255) / 256, 256, 0, stream>>>(d_in[0], af_c, N * 92, mode);
  cvtf_kernel<<<(E * 3 + 255) / 256, 256, 0, stream>>>(d_in[1], r_f, E * 3, mode);

  // ---- CSR builds + direct permuted indices ----
  hipMemsetAsync(cursors, 0, (size_t)N * 4, stream);
  count_kernel<<<E / 256, 256, 0, stream>>>(dst, cursors, E);
  scan_kernel<<<1, 256, 0, stream>>>(cursors, aoff, N);
  copy_kernel<<<(N + 255) / 256, 256, 0, stream>>>(aoff, cursors, N);
  fill_kernel<<<E / 256, 256, 0, stream>>>(dst, cursors, aids, E);

  hipMemsetAsync(cursors, 0, (size_t)E * 4, stream);
  count_kernel<<<T / 256, 256, 0, stream>>>(ldst, cursors, T);
  scan_kernel<<<1, 256, 0, stream>>>(cursors, loff, E);
  copy_kernel<<<(E + 255) / 256, 256, 0, stream>>>(loff, cursors, E);
  fill2_kernel<<<T / 256, 256, 0, stream>>>(ldst, lsrc, cursors, lsrc_p, ldst_p, T);

  // ---- weight transposes ----
  transpose_eggc_kernel<<<dim3(256, 60), 256, 0, stream>>>(d_in[26], WtE, mode);
  bias_perm_kernel<<<60, 256, 0, stream>>>(d_in[27], ebp, mode);
  transpose_pad_kernel<<<16, 256, 0, stream>>>(d_in[18], Wt_a1, 40, 64, 64, mode);
  transpose_pad_kernel<<<64, 256, 0, stream>>>(d_in[22], Wt_a2, 64, 256, 64, mode);
  transpose_pad_kernel<<<32, 256, 0, stream>>>(d_in[10], Wt_e1, 80, 64, 128, mode);
  transpose_pad_kernel<<<64, 256, 0, stream>>>(d_in[14], Wt_e2, 64, 256, 64, mode);

  // ---- cos / bondlength, then fused MLP pipelines ----
  cosbl_kernel<<<(T + E + 255) / 256, 256, 0, stream>>>(r_f, lsrc_p, ldst_p, cosv, blv, T, E);
  mlp1_ln_kernel<64, 40, 1><<<T / 128, 256, 0, stream>>>(
      cosv, Wt_a1, a_b1_c, a_l1s_c, a_l1b_c, emb_t, T);
  mlp2_ln_kernel<<<T / 64, 256, 0, stream>>>(emb_t, Wt_a2, a_b2_c, a_l2s_c, a_l2b_c, z, T);
  mlp1_ln_kernel<128, 80, 0><<<E / 128, 256, 0, stream>>>(
      blv, Wt_e1, e_b1_c, e_l1s_c, e_l1b_c, emb_e, E);
  mlp2_ln_kernel<<<E / 64, 256, 0, stream>>>(emb_e, Wt_e2, e_b2_c, e_l2s_c, e_l2b_c, y, E);

  // ---- x = MLP(atom_features) ----
  atom_init_kernel<<<N, 256, 0, stream>>>(af_c, atW_c, atom_b_c, atom_lns_c, atom_lnb_c, x);

  // ---- EGGC blocks ----
  auto atom_eggc = [&](int blk, int do_edge) {
    const bfu* W  = WtE + (size_t)blk * 5 * HH;
    const bfu* bb = ebp + (size_t)blk * 5 * H;
    const bfu* ls = els_c + (size_t)blk * 2 * H;
    const bfu* lb = elb_c + (size_t)blk * 2 * H;
    atom_gemm_kernel<<<dim3(512, 2), 256, 0, stream>>>(x, y, W, bb, afused, mbufa);
    int eblk = do_edge ? E / 8 : 0;
    atom_fused_kernel<<<eblk + N / 4, 256, 0, stream>>>(
        mbufa, afused, src, dst, x, y, aoff, aids, eblk, ls, lb, ls + H, lb + H);
  };

  auto line_eggc = [&](int blk, int do_edge) {
    const bfu* W  = WtE + (size_t)blk * 5 * HH;
    const bfu* bb = ebp + (size_t)blk * 5 * H;
    const bfu* ls = els_c + (size_t)blk * 2 * H;
    const bfu* lb = elb_c + (size_t)blk * 2 * H;
    // gates [E,768] + chunk-0 m/u3 into buffer 0
    line_gates_kernel<<<dim3(384, 9), 256, 0, stream>>>(
        y, z, W, bb, lfused, mchunk, u3c, loff);
    for (int c = 0; c < 24; ++c) {
      int n0 = c * CHN;
      const bfu* mA = mchunk + (size_t)(c & 1) * CHCAP * 256;
      bfu* mB = mchunk + (size_t)((c + 1) & 1) * CHCAP * 256;
      const bfu* u3A = u3c + (size_t)(c & 1) * CHN * 256;
      bfu* u3B = u3c + (size_t)((c + 1) & 1) * CHN * 256;
      int eblk = do_edge ? CHCAP / 8 : 0;
      int do_gemm = (c < 23);
      int grid = eblk + CHN / 4 + (CHCAP / 128) * 2 + 32;
      line_step_kernel<<<grid, 256, 0, stream>>>(
          z, y, lfused, W, bb, mA, mB, u3A, u3B, loff, lsrc_p, ldst_p,
          z, y, n0, eblk, do_gemm, ls, lb, ls + H, lb + H);
    }
  };

  for (int i = 0; i < 4; ++i) {
    atom_eggc(2 * i, 1);
    line_eggc(2 * i + 1, i < 3);   // block 7's z-update is dead
  }
  for (int i = 0; i < 4; ++i)
    atom_eggc(8 + i, i < 3);       // block 11's y-update is dead

  // ---- output ----
  hipMemsetAsync(macc, 0, 4, stream);
  final_kernel<<<N / 4, 256, 0, stream>>>(x, fcW_c, fcb_c, d_out, macc, mode);
  mean_kernel<<<1, 64, 0, stream>>>(macc, d_out, mode);
}

// Round 12
// 2618.708 us; speedup vs baseline: 1.3809x; 1.3809x over previous
//
#include <hip/hip_runtime.h>

// ALIGNN forward on MI355X. Round 11: round-9 skeleton (proven 2870us) +
// global_load_lds width-16 GEMM staging (LDT=64, m97 pattern) +
// mlp2_ln A-fragments direct from global (no LDS staging barrier).

typedef unsigned short bfu;
typedef __attribute__((ext_vector_type(8))) short short8;   // 8 bf16
typedef __attribute__((ext_vector_type(4))) float floatx4;  // MFMA C/D

#define CHN 4096        // dst nodes per line-graph chunk (12 chunks)
#define CHCAP 24576     // row capacity per chunk (mean 21845)
#define HH 65536        // 256*256

__device__ __forceinline__ float bf2f(bfu u) {
  union { unsigned u; float f; } x; x.u = ((unsigned)u) << 16; return x.f;
}
__device__ __forceinline__ bfu f2bf(float f) {
  union { float f; unsigned u; } x; x.f = f;
  unsigned r = x.u + 0x7FFFu + ((x.u >> 16) & 1u);  // RNE
  return (bfu)(r >> 16);
}
__device__ __forceinline__ float fsig(float x) {
  return __builtin_amdgcn_rcpf(1.f + __expf(-x));
}
__device__ __forceinline__ float fsilu(float x) { return x * fsig(x); }

// async 16B/lane global->LDS; lds base must be wave-uniform (dest = base + lane*16)
__device__ __forceinline__ void load_lds16(const bfu* g, bfu* l) {
  __builtin_amdgcn_global_load_lds(
      (const __attribute__((address_space(1))) void*)g,
      (__attribute__((address_space(3))) void*)l, 16, 0, 0);
}

// ---- 8-wide (16B/lane) row math over 32-lane groups ----
struct f8 { float v[8]; };
__device__ __forceinline__ f8 ld8(const bfu* p) {
  short8 u = *(const short8*)(const void*)p;
  f8 r;
#pragma unroll
  for (int i = 0; i < 8; ++i) r.v[i] = bf2f((bfu)u[i]);
  return r;
}
__device__ __forceinline__ void st8(bfu* p, f8 x) {
  short8 u;
#pragma unroll
  for (int i = 0; i < 8; ++i) u[i] = (short)f2bf(x.v[i]);
  *(short8*)(void*)p = u;
}
__device__ __forceinline__ f8 add8(f8 a, f8 b) {
  f8 r;
#pragma unroll
  for (int i = 0; i < 8; ++i) r.v[i] = a.v[i] + b.v[i];
  return r;
}
__device__ __forceinline__ f8 sig8(f8 m) {
  f8 r;
#pragma unroll
  for (int i = 0; i < 8; ++i) r.v[i] = fsig(m.v[i]);
  return r;
}
__device__ __forceinline__ void wstats32(const f8& x, float& mean, float& rstd) {
  float s = 0.f, q = 0.f;
#pragma unroll
  for (int i = 0; i < 8; ++i) { s += x.v[i]; q += x.v[i] * x.v[i]; }
#pragma unroll
  for (int m = 1; m < 32; m <<= 1) { s += __shfl_xor(s, m); q += __shfl_xor(q, m); }
  mean = s * (1.f / 256.f);
  rstd = rsqrtf(fmaxf(q * (1.f / 256.f) - mean * mean, 0.f) + 1e-5f);
}
__device__ __forceinline__ f8 lnsilu8(f8 pre, f8 sg, f8 bb) {
  float mean, rstd; wstats32(pre, mean, rstd);
  f8 r;
#pragma unroll
  for (int i = 0; i < 8; ++i)
    r.v[i] = fsilu((pre.v[i] - mean) * rstd * sg.v[i] + bb.v[i]);
  return r;
}

__device__ __forceinline__ float block_sum256(float t, float* sm) {
#pragma unroll
  for (int o = 32; o; o >>= 1) t += __shfl_down(t, o);
  if ((threadIdx.x & 63) == 0) sm[threadIdx.x >> 6] = t;
  __syncthreads();
  float r = sm[0] + sm[1] + sm[2] + sm[3];
  __syncthreads();
  return r;
}

// ------------------------------------------------------- dtype handling ----
__global__ void probe_kernel(const unsigned* __restrict__ ones_raw, int* __restrict__ mode) {
  if (threadIdx.x == 0) *mode = (ones_raw[0] == 0x3F800000u) ? 1 : 0;
}
__global__ __launch_bounds__(256) void cvt_kernel(
    const void* __restrict__ src, bfu* __restrict__ dst, int n, const int* __restrict__ mode) {
  int i = blockIdx.x * 256 + threadIdx.x;
  if (i >= n) return;
  dst[i] = (*mode) ? f2bf(((const float*)src)[i]) : ((const bfu*)src)[i];
}
__global__ __launch_bounds__(256) void cvtf_kernel(
    const void* __restrict__ src, float* __restrict__ dst, int n, const int* __restrict__ mode) {
  int i = blockIdx.x * 256 + threadIdx.x;
  if (i >= n) return;
  dst[i] = (*mode) ? ((const float*)src)[i] : bf2f(((const bfu*)src)[i]);
}
struct CvtDesc { const void* src; bfu* dst; int n; };
struct CvtPack { CvtDesc e[20]; };
__global__ __launch_bounds__(256) void cvt_batch_kernel(CvtPack p, const int* __restrict__ mode) {
  CvtDesc d = p.e[blockIdx.y];
  int i = blockIdx.x * 256 + threadIdx.x;
  if (i >= d.n) return;
  d.dst[i] = (*mode) ? f2bf(((const float*)d.src)[i]) : ((const bfu*)d.src)[i];
}

// ---------------------------------------------------------------- GEMM ----
// LDT = 64 (unpadded, linear layout) -> staging via global_load_lds x16.
template<int BM, int BN, int WR, int WC>
__device__ __forceinline__ void gemm_body(
    const bfu* __restrict__ A, const bfu* __restrict__ Bt,
    const bfu* __restrict__ bias, bfu* __restrict__ Cout,
    int cnt, int N, int K, int base, int m0, int n0)
{
  constexpr int WM = BM / WR, WN = BN / WC;
  constexpr int TM = WM / 16, TN = WN / 16;
  static __shared__ __align__(16) bfu As[BM * 64];
  static __shared__ __align__(16) bfu Bs[BN * 64];

  const int tid = threadIdx.x, wave = tid >> 6, lane = tid & 63;
  const int wr = wave / WC, wc = wave % WC;
  const int lrow = lane & 15, kq = (lane >> 4) * 8;

  floatx4 acc[TM][TN];
#pragma unroll
  for (int i = 0; i < TM; ++i)
#pragma unroll
    for (int j = 0; j < TN; ++j) acc[i][j] = (floatx4){0.f, 0.f, 0.f, 0.f};

  for (int k0 = 0; k0 < K; k0 += 64) {
#pragma unroll
    for (int it = 0; it < BM / 32; ++it) {       // BM*8 chunks / 256 threads
      int ch = it * 256 + tid;
      int row = ch >> 3, kc = (ch & 7) << 3;
      int r = m0 + row;
      int ar = base + (r < cnt ? r : cnt - 1);
      load_lds16(A + (size_t)ar * K + k0 + kc, As + (size_t)(it * 256 + wave * 64) * 8);
    }
#pragma unroll
    for (int it = 0; it < BN / 32; ++it) {
      int ch = it * 256 + tid;
      int row = ch >> 3, kc = (ch & 7) << 3;
      load_lds16(Bt + (size_t)(n0 + row) * K + k0 + kc, Bs + (size_t)(it * 256 + wave * 64) * 8);
    }
    __syncthreads();
#pragma unroll
    for (int s = 0; s < 2; ++s) {
      short8 Af[TM], Bf[TN];
#pragma unroll
      for (int i = 0; i < TM; ++i)
        Af[i] = *(const short8*)(const void*)(As + (wr * WM + i * 16 + lrow) * 64 + s * 32 + kq);
#pragma unroll
      for (int j = 0; j < TN; ++j)
        Bf[j] = *(const short8*)(const void*)(Bs + (wc * WN + j * 16 + lrow) * 64 + s * 32 + kq);
#pragma unroll
      for (int i = 0; i < TM; ++i)
#pragma unroll
        for (int j = 0; j < TN; ++j)
          acc[i][j] = __builtin_amdgcn_mfma_f32_16x16x32_bf16(Af[i], Bf[j], acc[i][j], 0, 0, 0);
    }
    __syncthreads();
  }

  const int rquad = lane >> 4, cin = lane & 15;
#pragma unroll
  for (int i = 0; i < TM; ++i) {
#pragma unroll
    for (int rr = 0; rr < 4; ++rr) {
      int orow = m0 + wr * WM + i * 16 + rquad * 4 + rr;
      if (orow >= cnt) continue;
#pragma unroll
      for (int j = 0; j < TN; ++j) {
        int gcol = n0 + wc * WN + j * 16 + cin;
        Cout[(size_t)orow * N + gcol] = f2bf(acc[i][j][rr] + bf2f(bias[gcol]));
      }
    }
  }
}

template<int BM, int BN, int WR, int WC>
__global__ __launch_bounds__(256) void gemm_kernel(
    const bfu* __restrict__ A, const bfu* __restrict__ Bt,
    const bfu* __restrict__ bias, bfu* __restrict__ Cout, int M, int N, int K)
{
  gemm_body<BM, BN, WR, WC>(A, Bt, bias, Cout, M, N, K, 0,
                            blockIdx.x * BM, blockIdx.y * BN);
}

// merged line-chunk GEMM: y<2 -> m tile (rows loff[n0..n1] of z); y==2 -> u3
__global__ __launch_bounds__(256) void line_gemm_kernel(
    const bfu* __restrict__ z, const bfu* __restrict__ yb,
    const bfu* __restrict__ W, const bfu* __restrict__ bb,
    bfu* __restrict__ mchunk, bfu* __restrict__ u3c,
    const int* __restrict__ loff, int n0, int n1)
{
  if (blockIdx.y < 2) {
    int base = loff[n0], cnt = loff[n1] - base;
    int m0 = blockIdx.x * 128;
    if (m0 >= cnt) return;
    gemm_body<128, 128, 2, 2>(z, W + 4 * HH, bb + 4 * 256, mchunk,
                              cnt, 256, 256, base, m0, blockIdx.y * 128);
  } else {
    if (blockIdx.x >= 64) return;
    gemm_body<128, 128, 2, 2>(yb + (size_t)n0 * 256, W + 3 * HH, bb + 3 * 256, u3c,
                              CHN, 256, 256, 0, (blockIdx.x & 31) * 128, (blockIdx.x >> 5) * 128);
  }
}

// merged atom gates + m launch: grid (512, 2)
__global__ __launch_bounds__(256) void atom_gemm_kernel(
    const bfu* __restrict__ x, const bfu* __restrict__ y,
    const bfu* __restrict__ W, const bfu* __restrict__ bb,
    bfu* __restrict__ afused, bfu* __restrict__ mbufa)
{
  if (blockIdx.x < 384) {
    gemm_body<128, 128, 2, 2>(y, W + 4 * HH, bb + 4 * 256, mbufa,
                              49152, 256, 256, 0, blockIdx.x * 128, blockIdx.y * 128);
  } else {
    int lid = (blockIdx.x - 384) * 2 + blockIdx.y;  // 0..255
    gemm_body<128, 128, 2, 2>(x, W, bb, afused,
                              4096, 1024, 256, 0, (lid >> 3) * 128, (lid & 7) * 128);
  }
}

// merged line gates + chunk-0 m/u3 GEMM: grid (384, 9)
__global__ __launch_bounds__(256) void line_gates_kernel(
    const bfu* __restrict__ y, const bfu* __restrict__ z,
    const bfu* __restrict__ W, const bfu* __restrict__ bb,
    bfu* __restrict__ lfused, bfu* __restrict__ mch0, bfu* __restrict__ u3c0,
    const int* __restrict__ loff)
{
  if (blockIdx.y < 6) {
    gemm_body<128, 128, 2, 2>(y, W, bb, lfused,
                              49152, 768, 256, 0, blockIdx.x * 128, blockIdx.y * 128);
  } else if (blockIdx.y < 8) {
    int cnt = loff[CHN];
    int m0 = blockIdx.x * 128;
    if (blockIdx.x >= CHCAP / 128 || m0 >= cnt) return;
    gemm_body<128, 128, 2, 2>(z, W + 4 * HH, bb + 4 * 256, mch0,
                              cnt, 256, 256, 0, m0, (blockIdx.y - 6) * 128);
  } else {
    if (blockIdx.x >= 64) return;
    gemm_body<128, 128, 2, 2>(y, W + 3 * HH, bb + 3 * 256, u3c0,
                              CHN, 256, 256, 0, (blockIdx.x & 31) * 128, (blockIdx.x >> 5) * 128);
  }
}

// --------------------------------------------- cos / bondlength precompute ----
__global__ __launch_bounds__(256) void cosbl_kernel(
    const float* __restrict__ r, const int* __restrict__ lsrc_p,
    const int* __restrict__ ldst_p, float* __restrict__ cosv,
    float* __restrict__ bl, int T, int E)
{
  int idx = blockIdx.x * 256 + threadIdx.x;
  if (idx < T) {
    int e1 = lsrc_p[idx], e2 = ldst_p[idx];
    float ax = -r[e1 * 3 + 0], ay = -r[e1 * 3 + 1], az = -r[e1 * 3 + 2];
    float bx =  r[e2 * 3 + 0], by =  r[e2 * 3 + 1], bz =  r[e2 * 3 + 2];
    float dot = ax * bx + ay * by + az * bz;
    float na = sqrtf(ax * ax + ay * ay + az * az);
    float nb = sqrtf(bx * bx + by * by + bz * bz);
    float c = dot / (na * nb);
    cosv[idx] = fminf(1.f, fmaxf(-1.f, c));
  } else if (idx < T + E) {
    int e = idx - T;
    float x = r[e * 3 + 0], yv = r[e * 3 + 1], zv = r[e * 3 + 2];
    bl[e] = sqrtf(x * x + yv * yv + zv * zv);
  }
}

// ------------------------- MLP1 fused: rbf(in staging) @ W1 + b1 -> LN64+SiLU
template<int KP, int BINS, int IS_ANG>
__global__ __launch_bounds__(256) void mlp1_ln_kernel(
    const float* __restrict__ v, const bfu* __restrict__ Bt,
    const bfu* __restrict__ bias, const bfu* __restrict__ lns,
    const bfu* __restrict__ lnb, bfu* __restrict__ outp, int M)
{
  constexpr int LDT = KP + 8;
  __shared__ bfu As[128 * LDT];
  const int tid = threadIdx.x, wave = tid >> 6, lane = tid & 63;
  const int lrow = lane & 15, kq = (lane >> 4) * 8;
  const int m0 = blockIdx.x * 128;

  for (int idx = tid; idx < 128 * (KP / 8); idx += 256) {
    int row = idx / (KP / 8), kc = (idx % (KP / 8)) * 8;
    float val = v[m0 + row];
    short8 pack;
#pragma unroll
    for (int jj = 0; jj < 8; ++jj) {
      int k = kc + jj;
      float e = 0.f;
      if (k < BINS) {
        float center = IS_ANG ? (-1.f + k * (2.f / 39.f)) : (k * (8.f / 79.f));
        float d = val - center;
        e = __expf((IS_ANG ? -19.5f : -9.875f) * d * d);
      }
      pack[jj] = (short)f2bf(e);
    }
    *(short8*)(void*)(As + row * LDT + kc) = pack;
  }
  __syncthreads();

  floatx4 acc[2][4];
#pragma unroll
  for (int i = 0; i < 2; ++i)
#pragma unroll
    for (int j = 0; j < 4; ++j) acc[i][j] = (floatx4){0.f, 0.f, 0.f, 0.f};
#pragma unroll
  for (int ks = 0; ks < KP / 32; ++ks) {
    short8 Af[2], Bf[4];
#pragma unroll
    for (int j = 0; j < 4; ++j)
      Bf[j] = *(const short8*)(const void*)(Bt + (size_t)(j * 16 + lrow) * KP + ks * 32 + kq);
#pragma unroll
    for (int i = 0; i < 2; ++i)
      Af[i] = *(const short8*)(const void*)(As + (wave * 32 + i * 16 + lrow) * LDT + ks * 32 + kq);
#pragma unroll
    for (int i = 0; i < 2; ++i)
#pragma unroll
      for (int j = 0; j < 4; ++j)
        acc[i][j] = __builtin_amdgcn_mfma_f32_16x16x32_bf16(Af[i], Bf[j], acc[i][j], 0, 0, 0);
  }

  const int rquad = lane >> 4, cin = lane & 15;
  float bj[4], sj[4], lj[4];
#pragma unroll
  for (int j = 0; j < 4; ++j) {
    bj[j] = bf2f(bias[j * 16 + cin]);
    sj[j] = bf2f(lns[j * 16 + cin]);
    lj[j] = bf2f(lnb[j * 16 + cin]);
  }
#pragma unroll
  for (int i = 0; i < 2; ++i) {
#pragma unroll
    for (int rr = 0; rr < 4; ++rr) {
      int row = m0 + wave * 32 + i * 16 + rquad * 4 + rr;
      float pre[4], s = 0.f, q = 0.f;
#pragma unroll
      for (int j = 0; j < 4; ++j) {
        pre[j] = acc[i][j][rr] + bj[j];
        s += pre[j]; q += pre[j] * pre[j];
      }
#pragma unroll
      for (int mm = 1; mm < 16; mm <<= 1) { s += __shfl_xor(s, mm); q += __shfl_xor(q, mm); }
      float mean = s * (1.f / 64.f);
      float rstd = rsqrtf(fmaxf(q * (1.f / 64.f) - mean * mean, 0.f) + 1e-5f);
#pragma unroll
      for (int j = 0; j < 4; ++j) {
        float u = (pre[j] - mean) * rstd * sj[j] + lj[j];
        outp[(size_t)row * 64 + j * 16 + cin] = f2bf(fsilu(u));
      }
    }
  }
}

// ------------- MLP2 fused: emb[M,64] @ W2 + b2 -> LN256+SiLU -> out[M,256]
// A and B both streamed from global (L2-hot); LDS only for LN partials.
__global__ __launch_bounds__(256) void mlp2_ln_kernel(
    const bfu* __restrict__ A, const bfu* __restrict__ Bt,
    const bfu* __restrict__ bias, const bfu* __restrict__ lns,
    const bfu* __restrict__ lnb, bfu* __restrict__ outp, int M)
{
  __shared__ float part[64 * 8];
  const int tid = threadIdx.x, wave = tid >> 6, lane = tid & 63;
  const int lrow = lane & 15, kq = (lane >> 4) * 8;
  const int m0 = blockIdx.x * 64;

  short8 Bf[2][4];
#pragma unroll
  for (int s = 0; s < 2; ++s)
#pragma unroll
    for (int j = 0; j < 4; ++j)
      Bf[s][j] = *(const short8*)(const void*)(
          Bt + (size_t)(wave * 64 + j * 16 + lrow) * 64 + s * 32 + kq);

  floatx4 acc[4][4];
#pragma unroll
  for (int i = 0; i < 4; ++i)
#pragma unroll
    for (int j = 0; j < 4; ++j) acc[i][j] = (floatx4){0.f, 0.f, 0.f, 0.f};
#pragma unroll
  for (int s = 0; s < 2; ++s) {
    short8 Af[4];
#pragma unroll
    for (int i = 0; i < 4; ++i)
      Af[i] = *(const short8*)(const void*)(
          A + (size_t)(m0 + i * 16 + lrow) * 64 + s * 32 + kq);
#pragma unroll
    for (int i = 0; i < 4; ++i)
#pragma unroll
      for (int j = 0; j < 4; ++j)
        acc[i][j] = __builtin_amdgcn_mfma_f32_16x16x32_bf16(Af[i], Bf[s][j], acc[i][j], 0, 0, 0);
  }

  const int rquad = lane >> 4, cin = lane & 15;
  float bj[4], sj[4], lj[4];
#pragma unroll
  for (int j = 0; j < 4; ++j) {
    int col = wave * 64 + j * 16 + cin;
    bj[j] = bf2f(bias[col]); sj[j] = bf2f(lns[col]); lj[j] = bf2f(lnb[col]);
  }
#pragma unroll
  for (int i = 0; i < 4; ++i) {
#pragma unroll
    for (int rr = 0; rr < 4; ++rr) {
      float s = 0.f, q = 0.f;
#pragma unroll
      for (int j = 0; j < 4; ++j) {
        float p = acc[i][j][rr] + bj[j];
        s += p; q += p * p;
      }
#pragma unroll
      for (int mm = 1; mm < 16; mm <<= 1) { s += __shfl_xor(s, mm); q += __shfl_xor(q, mm); }
      if (cin == 0) {
        int row = i * 16 + rquad * 4 + rr;
        part[row * 8 + wave * 2] = s;
        part[row * 8 + wave * 2 + 1] = q;
      }
    }
  }
  __syncthreads();
#pragma unroll
  for (int i = 0; i < 4; ++i) {
#pragma unroll
    for (int rr = 0; rr < 4; ++rr) {
      int row = i * 16 + rquad * 4 + rr;
      float s = part[row * 8] + part[row * 8 + 2] + part[row * 8 + 4] + part[row * 8 + 6];
      float q = part[row * 8 + 1] + part[row * 8 + 3] + part[row * 8 + 5] + part[row * 8 + 7];
      float mean = s * (1.f / 256.f);
      float rstd = rsqrtf(fmaxf(q * (1.f / 256.f) - mean * mean, 0.f) + 1e-5f);
#pragma unroll
      for (int j = 0; j < 4; ++j) {
        float u = (acc[i][j][rr] + bj[j] - mean) * rstd * sj[j] + lj[j];
        outp[(size_t)(m0 + row) * 256 + wave * 64 + j * 16 + cin] = f2bf(fsilu(u));
      }
    }
  }
}

// ----------------------------------------------------------- CSR build ----
__global__ __launch_bounds__(256) void count_kernel(
    const int* __restrict__ d, int* __restrict__ cnt, int ne) {
  int i = blockIdx.x * 256 + threadIdx.x;
  if (i < ne) atomicAdd(&cnt[d[i]], 1);
}
__global__ __launch_bounds__(256) void scan_kernel(
    const int* __restrict__ cnt, int* __restrict__ off, int n) {
  __shared__ int ssum[256];
  __shared__ int sbase[257];
  int t = threadIdx.x;
  int strip = (n + 255) / 256;
  int lo = t * strip, hi = lo + strip; if (hi > n) hi = n; if (lo > n) lo = n;
  int s = 0;
  for (int i = lo; i < hi; ++i) s += cnt[i];
  ssum[t] = s;
  __syncthreads();
  if (t == 0) {
    int run = 0;
    for (int i = 0; i < 256; ++i) { sbase[i] = run; run += ssum[i]; }
    sbase[256] = run;
  }
  __syncthreads();
  int run = sbase[t];
  for (int i = lo; i < hi; ++i) { off[i] = run; run += cnt[i]; }
  if (t == 0) off[n] = sbase[256];
}
__global__ __launch_bounds__(256) void copy_kernel(
    const int* __restrict__ a, int* __restrict__ b, int n) {
  int i = blockIdx.x * 256 + threadIdx.x;
  if (i < n) b[i] = a[i];
}
__global__ __launch_bounds__(256) void fill_kernel(
    const int* __restrict__ d, int* __restrict__ cur, int* __restrict__ ids, int ne) {
  int i = blockIdx.x * 256 + threadIdx.x;
  if (i < ne) ids[atomicAdd(&cur[d[i]], 1)] = i;
}
__global__ __launch_bounds__(256) void fill2_kernel(
    const int* __restrict__ ldst, const int* __restrict__ lsrc, int* __restrict__ cur,
    int* __restrict__ lsrc_p, int* __restrict__ ldst_p, int ne) {
  int i = blockIdx.x * 256 + threadIdx.x;
  if (i >= ne) return;
  int d = ldst[i];
  int pos = atomicAdd(&cur[d], 1);
  lsrc_p[pos] = lsrc[i];
  ldst_p[pos] = d;
}

// ------------------------------------------------------ weight transpose ----
__global__ __launch_bounds__(256) void transpose_pad_kernel(
    const void* __restrict__ W, bfu* __restrict__ Wt, int K, int N, int Kp,
    const int* __restrict__ mode)
{
  int idx = blockIdx.x * 256 + threadIdx.x;
  if (idx >= N * Kp) return;
  int n = idx / Kp, k = idx - n * Kp;
  bfu v = 0;
  if (k < K) {
    size_t si = (size_t)k * N + n;
    v = (*mode) ? f2bf(((const float*)W)[si]) : ((const bfu*)W)[si];
  }
  Wt[idx] = v;
}
// unified slot order: [W0, W4, W1, W3, W2] -> gates [g0|u4|g1(|u3)], m slot 4
__device__ __forceinline__ int slot2mat(int slot) {
  const int m[5] = {0, 4, 1, 3, 2};
  return m[slot];
}
__global__ __launch_bounds__(256) void transpose_eggc_kernel(
    const void* __restrict__ W, bfu* __restrict__ Wt, const int* __restrict__ mode)
{
  int bs = blockIdx.y;
  int blk = bs / 5, slot = bs - blk * 5;
  int mat = slot2mat(slot);
  int idx = blockIdx.x * 256 + threadIdx.x;
  int n = idx >> 8, k = idx & 255;
  size_t si = ((size_t)(blk * 5 + mat) * 256 + k) * 256 + n;
  bfu v = (*mode) ? f2bf(((const float*)W)[si]) : ((const bfu*)W)[si];
  Wt[((size_t)bs * 256 + n) * 256 + k] = v;
}
__global__ __launch_bounds__(256) void bias_perm_kernel(
    const void* __restrict__ B, bfu* __restrict__ Bp, const int* __restrict__ mode)
{
  int i = blockIdx.x * 256 + threadIdx.x;
  int bs = i >> 8, c = i & 255;
  int blk = bs / 5, slot = bs - blk * 5;
  int mat = slot2mat(slot);
  size_t si = (size_t)(blk * 5 + mat) * 256 + c;
  Bp[i] = (*mode) ? f2bf(((const float*)B)[si]) : ((const bfu*)B)[si];
}

// -------------------------------------------------- atom fused edge+agg ----
__global__ __launch_bounds__(256) void atom_fused_kernel(
    const bfu* __restrict__ mbuf, const bfu* __restrict__ af,
    const int* __restrict__ src, const int* __restrict__ dst,
    bfu* __restrict__ X, bfu* __restrict__ Y,
    const int* __restrict__ aoff, const int* __restrict__ aids,
    int eblk,
    const bfu* __restrict__ lns, const bfu* __restrict__ lnb,
    const bfu* __restrict__ les, const bfu* __restrict__ leb)
{
  int wave = threadIdx.x >> 6, lane = threadIdx.x & 63;
  int half = lane >> 5, c8 = (lane & 31) * 8;
  if ((int)blockIdx.x < eblk) {
    int e = blockIdx.x * 8 + wave * 2 + half;
    f8 m = add8(add8(ld8(mbuf + (size_t)e * 256 + c8),
                     ld8(af + (size_t)src[e] * 1024 + c8)),
                ld8(af + (size_t)dst[e] * 1024 + 512 + c8));
    f8 sil = lnsilu8(m, ld8(les + c8), ld8(leb + c8));
    bfu* op = Y + (size_t)e * 256 + c8;
    st8(op, add8(sil, ld8(op)));
  } else {
    int n = (blockIdx.x - eblk) * 4 + wave;
    int p0 = aoff[n], p1 = aoff[n + 1];
    f8 g1 = ld8(af + (size_t)n * 1024 + 512 + c8);
    f8 num = {}, den = {};
    for (int p = p0 + half; p < p1; p += 2) {
      int id = aids[p], sx = src[id];
      f8 m = add8(add8(ld8(mbuf + (size_t)id * 256 + c8),
                       ld8(af + (size_t)sx * 1024 + c8)), g1);
      f8 sg = sig8(m);
      f8 u4 = ld8(af + (size_t)sx * 1024 + 256 + c8);
#pragma unroll
      for (int i = 0; i < 8; ++i) {
        num.v[i] += sg.v[i] * u4.v[i];
        den.v[i] += sg.v[i];
      }
    }
#pragma unroll
    for (int i = 0; i < 8; ++i) {
      num.v[i] += __shfl_xor(num.v[i], 32);
      den.v[i] += __shfl_xor(den.v[i], 32);
    }
    f8 u3 = ld8(af + (size_t)n * 1024 + 768 + c8);
    f8 pre;
#pragma unroll
    for (int i = 0; i < 8; ++i)
      pre.v[i] = u3.v[i] + num.v[i] / (den.v[i] + 1e-6f);
    f8 sil = lnsilu8(pre, ld8(lns + c8), ld8(lnb + c8));
    if (half == 0) {
      bfu* op = X + (size_t)n * 256 + c8;
      st8(op, add8(sil, ld8(op)));
    }
  }
}

// -------------------------------------------------- line fused edge+agg ----
__global__ __launch_bounds__(256) void line_fused_kernel(
    const bfu* __restrict__ mchunk, const bfu* __restrict__ lf,
    const bfu* __restrict__ u3c,
    const int* __restrict__ loff, const int* __restrict__ lsrc_p,
    const int* __restrict__ ldst_p,
    bfu* __restrict__ Z, bfu* __restrict__ Y,
    int n0, int eblk,
    const bfu* __restrict__ lns, const bfu* __restrict__ lnb,
    const bfu* __restrict__ les, const bfu* __restrict__ leb)
{
  int wave = threadIdx.x >> 6, lane = threadIdx.x & 63;
  int half = lane >> 5, c8 = (lane & 31) * 8;
  int base = loff[n0];
  if ((int)blockIdx.x < eblk) {
    int rloc = blockIdx.x * 8 + wave * 2 + half;
    int cnt = loff[n0 + CHN] - base;
    if (rloc >= cnt) return;
    int p = base + rloc;
    f8 m = add8(add8(ld8(mchunk + (size_t)rloc * 256 + c8),
                     ld8(lf + (size_t)lsrc_p[p] * 768 + c8)),
                ld8(lf + (size_t)ldst_p[p] * 768 + 512 + c8));
    f8 sil = lnsilu8(m, ld8(les + c8), ld8(leb + c8));
    bfu* op = Z + (size_t)p * 256 + c8;
    st8(op, add8(sil, ld8(op)));
  } else {
    int n = n0 + (blockIdx.x - eblk) * 4 + wave;
    int p0 = loff[n], p1 = loff[n + 1];
    f8 g1 = ld8(lf + (size_t)n * 768 + 512 + c8);
    f8 num = {}, den = {};
    for (int p = p0 + half; p < p1; p += 2) {
      int sx = lsrc_p[p];
      f8 m = add8(add8(ld8(mchunk + (size_t)(p - base) * 256 + c8),
                       ld8(lf + (size_t)sx * 768 + c8)), g1);
      f8 sg = sig8(m);
      f8 u4 = ld8(lf + (size_t)sx * 768 + 256 + c8);
#pragma unroll
      for (int i = 0; i < 8; ++i) {
        num.v[i] += sg.v[i] * u4.v[i];
        den.v[i] += sg.v[i];
      }
    }
#pragma unroll
    for (int i = 0; i < 8; ++i) {
      num.v[i] += __shfl_xor(num.v[i], 32);
      den.v[i] += __shfl_xor(den.v[i], 32);
    }
    f8 u3 = ld8(u3c + (size_t)(n - n0) * 256 + c8);
    f8 pre;
#pragma unroll
    for (int i = 0; i < 8; ++i)
      pre.v[i] = u3.v[i] + num.v[i] / (den.v[i] + 1e-6f);
    f8 sil = lnsilu8(pre, ld8(lns + c8), ld8(lnb + c8));
    if (half == 0) {
      bfu* op = Y + (size_t)n * 256 + c8;
      st8(op, add8(sil, ld8(op)));
    }
  }
}

// ----------------------------------------------------------- atom init ----
__global__ __launch_bounds__(256) void atom_init_kernel(
    const bfu* __restrict__ af, const bfu* __restrict__ W, const bfu* __restrict__ bias,
    const bfu* __restrict__ lns, const bfu* __restrict__ lnb, bfu* __restrict__ X)
{
  __shared__ float sm[4];
  int row = blockIdx.x, c = threadIdx.x;
  float acc = bf2f(bias[c]);
  for (int k = 0; k < 92; ++k)
    acc += bf2f(af[row * 92 + k]) * bf2f(W[k * 256 + c]);
  float mean = block_sum256(acc, sm) * (1.f / 256.f);
  float d = acc - mean;
  float var = block_sum256(d * d, sm) * (1.f / 256.f);
  float u = d * rsqrtf(var + 1e-5f) * bf2f(lns[c]) + bf2f(lnb[c]);
  X[(size_t)row * 256 + c] = f2bf(fsilu(u));
}

// --------------------------------------------------------------- final ----
__global__ __launch_bounds__(256) void final_kernel(
    const bfu* __restrict__ X, const bfu* __restrict__ fcW, const bfu* __restrict__ fcb,
    void* __restrict__ out, float* __restrict__ acc, const int* __restrict__ mode)
{
  int row = blockIdx.x * 4 + (threadIdx.x >> 6);
  int lane = threadIdx.x & 63;
  float s = 0.f;
#pragma unroll
  for (int k = 0; k < 4; ++k)
    s += bf2f(X[(size_t)row * 256 + lane + k * 64]) * bf2f(fcW[lane + k * 64]);
#pragma unroll
  for (int o = 32; o; o >>= 1) s += __shfl_down(s, o);
  if (lane == 0) {
    float v = s + bf2f(fcb[0]);
    if (*mode) ((float*)out)[1 + row] = v;
    else       ((bfu*)out)[1 + row] = f2bf(v);
    atomicAdd(acc, v);
  }
}
__global__ void mean_kernel(const float* __restrict__ acc, void* __restrict__ out,
                            const int* __restrict__ mode) {
  if (threadIdx.x == 0) {
    float v = acc[0] * (1.f / 4096.f);
    if (*mode) ((float*)out)[0] = v;
    else       ((bfu*)out)[0] = f2bf(v);
  }
}
__global__ void dbg_kernel(void* __restrict__ out, float v) {
  if (threadIdx.x == 0) { ((bfu*)out)[0] = f2bf(v); }
}

// ---------------------------------------------------------------- host ----
extern "C" void kernel_launch(void* const* d_in, const int* in_sizes, int n_in,
                              void* d_out, int out_size, void* d_ws, size_t ws_size,
                              hipStream_t stream) {
  const int N = 4096, E = 49152, T = 262144, H = 256;

  const int* src  = (const int*)d_in[2];
  const int* dst  = (const int*)d_in[3];
  const int* lsrc = (const int*)d_in[4];
  const int* ldst = (const int*)d_in[5];

  // ---- workspace carve (round-9 proven ~251 MB) ----
  char* bp = (char*)d_ws;
  size_t off = 0;
  auto carve = [&](size_t bytes) -> char* {
    char* q = bp + off;
    off = (off + bytes + 255) & ~(size_t)255;
    return q;
  };
  bfu* x       = (bfu*)carve((size_t)N * H * 2);
  bfu* y       = (bfu*)carve((size_t)E * H * 2);
  bfu* z       = (bfu*)carve((size_t)T * H * 2);       // ldst-sorted
  bfu* reg     = (bfu*)carve((size_t)E * 768 * 2);
  bfu* u3c     = (bfu*)carve((size_t)CHN * H * 2);
  bfu* mchunk  = (bfu*)carve((size_t)CHCAP * H * 2);
  bfu* WtE     = (bfu*)carve((size_t)60 * H * H * 2);  // slot-ordered
  bfu* ebp     = (bfu*)carve((size_t)12 * 5 * H * 2);
  bfu* Wt_a1   = (bfu*)carve(64 * 64 * 2);
  bfu* Wt_a2   = (bfu*)carve(256 * 64 * 2);
  bfu* Wt_e1   = (bfu*)carve(64 * 128 * 2);
  bfu* Wt_e2   = (bfu*)carve(256 * 64 * 2);
  int* aoff    = (int*)carve((size_t)(N + 1) * 4);
  int* aids    = (int*)carve((size_t)E * 4);
  int* loff    = (int*)carve((size_t)(E + 1) * 4);
  int* lsrc_p  = (int*)carve((size_t)T * 4);
  int* ldst_p  = (int*)carve((size_t)T * 4);
  int* cursors = (int*)carve((size_t)E * 4);
  float* macc  = (float*)carve(256);
  int* mode    = (int*)carve(256);
  bfu* par_c   = (bfu*)carve(8192 * 2);
  bfu* els_c   = (bfu*)carve((size_t)12 * 2 * H * 2);
  bfu* elb_c   = (bfu*)carve((size_t)12 * 2 * H * 2);

  if (off > ws_size) {
    hipMemsetAsync(d_out, 0, (size_t)out_size * 2, stream);
    dbg_kernel<<<1, 64, 0, stream>>>(d_out, (float)(ws_size >> 20));
    return;
  }

  // early-phase scratch in reg tail
  char* tail = (char*)reg + (size_t)52 * 1024 * 1024;
  bfu* af_c  = (bfu*)tail;                 tail += ((size_t)N * 92 * 2 + 255) & ~255ull;
  float* r_f = (float*)tail;               tail += ((size_t)E * 3 * 4 + 255) & ~255ull;
  float* cosv = (float*)tail;              tail += ((size_t)T * 4 + 255) & ~255ull;
  float* blv = (float*)tail;               tail += ((size_t)E * 4 + 255) & ~255ull;
  bfu* atW_c = (bfu*)tail;

  // packed small params
  bfu* atom_b_c   = par_c + 0;
  bfu* atom_lns_c = par_c + 256;
  bfu* atom_lnb_c = par_c + 512;
  bfu* e_b1_c     = par_c + 768;
  bfu* e_l1s_c    = par_c + 832;
  bfu* e_l1b_c    = par_c + 896;
  bfu* e_b2_c     = par_c + 1024;
  bfu* e_l2s_c    = par_c + 1280;
  bfu* e_l2b_c    = par_c + 1536;
  bfu* a_b1_c     = par_c + 1792;
  bfu* a_l1s_c    = par_c + 1856;
  bfu* a_l1b_c    = par_c + 1920;
  bfu* a_b2_c     = par_c + 2048;
  bfu* a_l2s_c    = par_c + 2304;
  bfu* a_l2b_c    = par_c + 2560;
  bfu* fcW_c      = par_c + 2816;
  bfu* fcb_c      = par_c + 3072;

  // overlays within reg
  bfu* lfused = reg;                        // line: [E,768] g0|u4|g1
  bfu* afused = reg;                        // atom: [N,1024] g0|u4|g1|u3
  bfu* mbufa  = reg + (size_t)N * 1024;     // atom: [E,256] m_raw
  bfu* emb_t  = reg;                        // early: [T,64]
  bfu* emb_e  = reg + (size_t)T * 64;       // early: [E,64]

  // ---- dtype probe + param conversion ----
  probe_kernel<<<1, 64, 0, stream>>>((const unsigned*)d_in[8], mode);
  CvtPack pk;
  int ii = 0;
  auto add = [&](int idx, bfu* dstp, int n) { pk.e[ii++] = {d_in[idx], dstp, n}; };
  add(7, atom_b_c, 256);  add(8, atom_lns_c, 256); add(9, atom_lnb_c, 256);
  add(11, e_b1_c, 64);    add(12, e_l1s_c, 64);    add(13, e_l1b_c, 64);
  add(15, e_b2_c, 256);   add(16, e_l2s_c, 256);   add(17, e_l2b_c, 256);
  add(19, a_b1_c, 64);    add(20, a_l1s_c, 64);    add(21, a_l1b_c, 64);
  add(23, a_b2_c, 256);   add(24, a_l2s_c, 256);   add(25, a_l2b_c, 256);
  add(30, fcW_c, 256);    add(31, fcb_c, 1);
  add(28, els_c, 12 * 2 * 256);
  add(29, elb_c, 12 * 2 * 256);
  add(6, atW_c, 92 * 256);
  cvt_batch_kernel<<<dim3(92, 20), 256, 0, stream>>>(pk, mode);
  cvt_kernel<<<(N * 92 + 255) / 256, 256, 0, stream>>>(d_in[0], af_c, N * 92, mode);
  cvtf_kernel<<<(E * 3 + 255) / 256, 256, 0, stream>>>(d_in[1], r_f, E * 3, mode);

  // ---- CSR builds + direct permuted indices ----
  hipMemsetAsync(cursors, 0, (size_t)N * 4, stream);
  count_kernel<<<E / 256, 256, 0, stream>>>(dst, cursors, E);
  scan_kernel<<<1, 256, 0, stream>>>(cursors, aoff, N);
  copy_kernel<<<(N + 255) / 256, 256, 0, stream>>>(aoff, cursors, N);
  fill_kernel<<<E / 256, 256, 0, stream>>>(dst, cursors, aids, E);

  hipMemsetAsync(cursors, 0, (size_t)E * 4, stream);
  count_kernel<<<T / 256, 256, 0, stream>>>(ldst, cursors, T);
  scan_kernel<<<1, 256, 0, stream>>>(cursors, loff, E);
  copy_kernel<<<(E + 255) / 256, 256, 0, stream>>>(loff, cursors, E);
  fill2_kernel<<<T / 256, 256, 0, stream>>>(ldst, lsrc, cursors, lsrc_p, ldst_p, T);

  // ---- weight transposes ----
  transpose_eggc_kernel<<<dim3(256, 60), 256, 0, stream>>>(d_in[26], WtE, mode);
  bias_perm_kernel<<<60, 256, 0, stream>>>(d_in[27], ebp, mode);
  transpose_pad_kernel<<<16, 256, 0, stream>>>(d_in[18], Wt_a1, 40, 64, 64, mode);
  transpose_pad_kernel<<<64, 256, 0, stream>>>(d_in[22], Wt_a2, 64, 256, 64, mode);
  transpose_pad_kernel<<<32, 256, 0, stream>>>(d_in[10], Wt_e1, 80, 64, 128, mode);
  transpose_pad_kernel<<<64, 256, 0, stream>>>(d_in[14], Wt_e2, 64, 256, 64, mode);

  // ---- cos / bondlength, then fused MLP pipelines ----
  cosbl_kernel<<<(T + E + 255) / 256, 256, 0, stream>>>(r_f, lsrc_p, ldst_p, cosv, blv, T, E);
  mlp1_ln_kernel<64, 40, 1><<<T / 128, 256, 0, stream>>>(
      cosv, Wt_a1, a_b1_c, a_l1s_c, a_l1b_c, emb_t, T);
  mlp2_ln_kernel<<<T / 64, 256, 0, stream>>>(emb_t, Wt_a2, a_b2_c, a_l2s_c, a_l2b_c, z, T);
  mlp1_ln_kernel<128, 80, 0><<<E / 128, 256, 0, stream>>>(
      blv, Wt_e1, e_b1_c, e_l1s_c, e_l1b_c, emb_e, E);
  mlp2_ln_kernel<<<E / 64, 256, 0, stream>>>(emb_e, Wt_e2, e_b2_c, e_l2s_c, e_l2b_c, y, E);

  // ---- x = MLP(atom_features) ----
  atom_init_kernel<<<N, 256, 0, stream>>>(af_c, atW_c, atom_b_c, atom_lns_c, atom_lnb_c, x);

  // ---- EGGC blocks ----
  auto atom_eggc = [&](int blk, int do_edge) {
    const bfu* W  = WtE + (size_t)blk * 5 * HH;
    const bfu* bb = ebp + (size_t)blk * 5 * H;
    const bfu* ls = els_c + (size_t)blk * 2 * H;
    const bfu* lb = elb_c + (size_t)blk * 2 * H;
    atom_gemm_kernel<<<dim3(512, 2), 256, 0, stream>>>(x, y, W, bb, afused, mbufa);
    int eblk = do_edge ? E / 8 : 0;
    atom_fused_kernel<<<eblk + N / 4, 256, 0, stream>>>(
        mbufa, afused, src, dst, x, y, aoff, aids, eblk, ls, lb, ls + H, lb + H);
  };

  auto line_eggc = [&](int blk, int do_edge) {
    const bfu* W  = WtE + (size_t)blk * 5 * HH;
    const bfu* bb = ebp + (size_t)blk * 5 * H;
    const bfu* ls = els_c + (size_t)blk * 2 * H;
    const bfu* lb = elb_c + (size_t)blk * 2 * H;
    // gates [E,768] + chunk-0 m/u3 in one launch
    line_gates_kernel<<<dim3(384, 9), 256, 0, stream>>>(
        y, z, W, bb, lfused, mchunk, u3c, loff);
    for (int c = 0; c < E / CHN; ++c) {
      int n0 = c * CHN;
      int eblk = do_edge ? CHCAP / 8 : 0;
      line_fused_kernel<<<eblk + CHN / 4, 256, 0, stream>>>(
          mchunk, lfused, u3c, loff, lsrc_p, ldst_p, z, y, n0, eblk,
          ls, lb, ls + H, lb + H);
      if (c + 1 < E / CHN)
        line_gemm_kernel<<<dim3(CHCAP / 128, 3), 256, 0, stream>>>(
            z, y, W, bb, mchunk, u3c, loff, n0 + CHN, n0 + 2 * CHN);
    }
  };

  for (int i = 0; i < 4; ++i) {
    atom_eggc(2 * i, 1);
    line_eggc(2 * i + 1, i < 3);   // block 7's z-update is dead
  }
  for (int i = 0; i < 4; ++i)
    atom_eggc(8 + i, i < 3);       // block 11's y-update is dead

  // ---- output ----
  hipMemsetAsync(macc, 0, 4, stream);
  final_kernel<<<N / 4, 256, 0, stream>>>(x, fcW_c, fcb_c, d_out, macc, mode);
  mean_kernel<<<1, 64, 0, stream>>>(macc, d_out, mode);
}

// Round 13
// 2564.021 us; speedup vs baseline: 1.4103x; 1.0213x over previous
//
#include <hip/hip_runtime.h>

// ALIGNN forward on MI355X. Round 12: round-11 base (2619us proven) +
// single-pass aggregation: edge z/y-update folded into node CSR loop
// (each edge's m / g0|u4 rows loaded exactly once; g1 hoisted per node).

typedef unsigned short bfu;
typedef __attribute__((ext_vector_type(8))) short short8;   // 8 bf16
typedef __attribute__((ext_vector_type(4))) float floatx4;  // MFMA C/D

#define CHN 4096        // dst nodes per line-graph chunk (12 chunks)
#define CHCAP 24576     // row capacity per chunk (mean 21845)
#define HH 65536        // 256*256

__device__ __forceinline__ float bf2f(bfu u) {
  union { unsigned u; float f; } x; x.u = ((unsigned)u) << 16; return x.f;
}
__device__ __forceinline__ bfu f2bf(float f) {
  union { float f; unsigned u; } x; x.f = f;
  unsigned r = x.u + 0x7FFFu + ((x.u >> 16) & 1u);  // RNE
  return (bfu)(r >> 16);
}
__device__ __forceinline__ float fsig(float x) {
  return __builtin_amdgcn_rcpf(1.f + __expf(-x));
}
__device__ __forceinline__ float fsilu(float x) { return x * fsig(x); }

// async 16B/lane global->LDS; lds base must be wave-uniform
__device__ __forceinline__ void load_lds16(const bfu* g, bfu* l) {
  __builtin_amdgcn_global_load_lds(
      (const __attribute__((address_space(1))) void*)g,
      (__attribute__((address_space(3))) void*)l, 16, 0, 0);
}

// ---- 8-wide (16B/lane) row math over 32-lane groups ----
struct f8 { float v[8]; };
__device__ __forceinline__ f8 ld8(const bfu* p) {
  short8 u = *(const short8*)(const void*)p;
  f8 r;
#pragma unroll
  for (int i = 0; i < 8; ++i) r.v[i] = bf2f((bfu)u[i]);
  return r;
}
__device__ __forceinline__ void st8(bfu* p, f8 x) {
  short8 u;
#pragma unroll
  for (int i = 0; i < 8; ++i) u[i] = (short)f2bf(x.v[i]);
  *(short8*)(void*)p = u;
}
__device__ __forceinline__ f8 add8(f8 a, f8 b) {
  f8 r;
#pragma unroll
  for (int i = 0; i < 8; ++i) r.v[i] = a.v[i] + b.v[i];
  return r;
}
__device__ __forceinline__ f8 sig8(f8 m) {
  f8 r;
#pragma unroll
  for (int i = 0; i < 8; ++i) r.v[i] = fsig(m.v[i]);
  return r;
}
__device__ __forceinline__ void wstats32(const f8& x, float& mean, float& rstd) {
  float s = 0.f, q = 0.f;
#pragma unroll
  for (int i = 0; i < 8; ++i) { s += x.v[i]; q += x.v[i] * x.v[i]; }
#pragma unroll
  for (int m = 1; m < 32; m <<= 1) { s += __shfl_xor(s, m); q += __shfl_xor(q, m); }
  mean = s * (1.f / 256.f);
  rstd = rsqrtf(fmaxf(q * (1.f / 256.f) - mean * mean, 0.f) + 1e-5f);
}
__device__ __forceinline__ f8 lnsilu8(f8 pre, f8 sg, f8 bb) {
  float mean, rstd; wstats32(pre, mean, rstd);
  f8 r;
#pragma unroll
  for (int i = 0; i < 8; ++i)
    r.v[i] = fsilu((pre.v[i] - mean) * rstd * sg.v[i] + bb.v[i]);
  return r;
}

__device__ __forceinline__ float block_sum256(float t, float* sm) {
#pragma unroll
  for (int o = 32; o; o >>= 1) t += __shfl_down(t, o);
  if ((threadIdx.x & 63) == 0) sm[threadIdx.x >> 6] = t;
  __syncthreads();
  float r = sm[0] + sm[1] + sm[2] + sm[3];
  __syncthreads();
  return r;
}

// ------------------------------------------------------- dtype handling ----
__global__ void probe_kernel(const unsigned* __restrict__ ones_raw, int* __restrict__ mode) {
  if (threadIdx.x == 0) *mode = (ones_raw[0] == 0x3F800000u) ? 1 : 0;
}
__global__ __launch_bounds__(256) void cvt_kernel(
    const void* __restrict__ src, bfu* __restrict__ dst, int n, const int* __restrict__ mode) {
  int i = blockIdx.x * 256 + threadIdx.x;
  if (i >= n) return;
  dst[i] = (*mode) ? f2bf(((const float*)src)[i]) : ((const bfu*)src)[i];
}
__global__ __launch_bounds__(256) void cvtf_kernel(
    const void* __restrict__ src, float* __restrict__ dst, int n, const int* __restrict__ mode) {
  int i = blockIdx.x * 256 + threadIdx.x;
  if (i >= n) return;
  dst[i] = (*mode) ? ((const float*)src)[i] : bf2f(((const bfu*)src)[i]);
}
struct CvtDesc { const void* src; bfu* dst; int n; };
struct CvtPack { CvtDesc e[20]; };
__global__ __launch_bounds__(256) void cvt_batch_kernel(CvtPack p, const int* __restrict__ mode) {
  CvtDesc d = p.e[blockIdx.y];
  int i = blockIdx.x * 256 + threadIdx.x;
  if (i >= d.n) return;
  d.dst[i] = (*mode) ? f2bf(((const float*)d.src)[i]) : ((const bfu*)d.src)[i];
}

// ---------------------------------------------------------------- GEMM ----
// LDT = 64 (unpadded) -> staging via global_load_lds x16 (m97 pattern).
template<int BM, int BN, int WR, int WC>
__device__ __forceinline__ void gemm_body(
    const bfu* __restrict__ A, const bfu* __restrict__ Bt,
    const bfu* __restrict__ bias, bfu* __restrict__ Cout,
    int cnt, int N, int K, int base, int m0, int n0)
{
  constexpr int WM = BM / WR, WN = BN / WC;
  constexpr int TM = WM / 16, TN = WN / 16;
  static __shared__ __align__(16) bfu As[BM * 64];
  static __shared__ __align__(16) bfu Bs[BN * 64];

  const int tid = threadIdx.x, wave = tid >> 6, lane = tid & 63;
  const int wr = wave / WC, wc = wave % WC;
  const int lrow = lane & 15, kq = (lane >> 4) * 8;

  floatx4 acc[TM][TN];
#pragma unroll
  for (int i = 0; i < TM; ++i)
#pragma unroll
    for (int j = 0; j < TN; ++j) acc[i][j] = (floatx4){0.f, 0.f, 0.f, 0.f};

  for (int k0 = 0; k0 < K; k0 += 64) {
#pragma unroll
    for (int it = 0; it < BM / 32; ++it) {
      int ch = it * 256 + tid;
      int row = ch >> 3, kc = (ch & 7) << 3;
      int r = m0 + row;
      int ar = base + (r < cnt ? r : cnt - 1);
      load_lds16(A + (size_t)ar * K + k0 + kc, As + (size_t)(it * 256 + wave * 64) * 8);
    }
#pragma unroll
    for (int it = 0; it < BN / 32; ++it) {
      int ch = it * 256 + tid;
      int row = ch >> 3, kc = (ch & 7) << 3;
      load_lds16(Bt + (size_t)(n0 + row) * K + k0 + kc, Bs + (size_t)(it * 256 + wave * 64) * 8);
    }
    __syncthreads();
#pragma unroll
    for (int s = 0; s < 2; ++s) {
      short8 Af[TM], Bf[TN];
#pragma unroll
      for (int i = 0; i < TM; ++i)
        Af[i] = *(const short8*)(const void*)(As + (wr * WM + i * 16 + lrow) * 64 + s * 32 + kq);
#pragma unroll
      for (int j = 0; j < TN; ++j)
        Bf[j] = *(const short8*)(const void*)(Bs + (wc * WN + j * 16 + lrow) * 64 + s * 32 + kq);
#pragma unroll
      for (int i = 0; i < TM; ++i)
#pragma unroll
        for (int j = 0; j < TN; ++j)
          acc[i][j] = __builtin_amdgcn_mfma_f32_16x16x32_bf16(Af[i], Bf[j], acc[i][j], 0, 0, 0);
    }
    __syncthreads();
  }

  const int rquad = lane >> 4, cin = lane & 15;
#pragma unroll
  for (int i = 0; i < TM; ++i) {
#pragma unroll
    for (int rr = 0; rr < 4; ++rr) {
      int orow = m0 + wr * WM + i * 16 + rquad * 4 + rr;
      if (orow >= cnt) continue;
#pragma unroll
      for (int j = 0; j < TN; ++j) {
        int gcol = n0 + wc * WN + j * 16 + cin;
        Cout[(size_t)orow * N + gcol] = f2bf(acc[i][j][rr] + bf2f(bias[gcol]));
      }
    }
  }
}

template<int BM, int BN, int WR, int WC>
__global__ __launch_bounds__(256) void gemm_kernel(
    const bfu* __restrict__ A, const bfu* __restrict__ Bt,
    const bfu* __restrict__ bias, bfu* __restrict__ Cout, int M, int N, int K)
{
  gemm_body<BM, BN, WR, WC>(A, Bt, bias, Cout, M, N, K, 0,
                            blockIdx.x * BM, blockIdx.y * BN);
}

// merged line-chunk GEMM: y<2 -> m tile (rows loff[n0..n1] of z); y==2 -> u3
__global__ __launch_bounds__(256) void line_gemm_kernel(
    const bfu* __restrict__ z, const bfu* __restrict__ yb,
    const bfu* __restrict__ W, const bfu* __restrict__ bb,
    bfu* __restrict__ mchunk, bfu* __restrict__ u3c,
    const int* __restrict__ loff, int n0, int n1)
{
  if (blockIdx.y < 2) {
    int base = loff[n0], cnt = loff[n1] - base;
    int m0 = blockIdx.x * 128;
    if (m0 >= cnt) return;
    gemm_body<128, 128, 2, 2>(z, W + 4 * HH, bb + 4 * 256, mchunk,
                              cnt, 256, 256, base, m0, blockIdx.y * 128);
  } else {
    if (blockIdx.x >= 64) return;
    gemm_body<128, 128, 2, 2>(yb + (size_t)n0 * 256, W + 3 * HH, bb + 3 * 256, u3c,
                              CHN, 256, 256, 0, (blockIdx.x & 31) * 128, (blockIdx.x >> 5) * 128);
  }
}

// merged atom gates + m launch: grid (512, 2)
__global__ __launch_bounds__(256) void atom_gemm_kernel(
    const bfu* __restrict__ x, const bfu* __restrict__ y,
    const bfu* __restrict__ W, const bfu* __restrict__ bb,
    bfu* __restrict__ afused, bfu* __restrict__ mbufa)
{
  if (blockIdx.x < 384) {
    gemm_body<128, 128, 2, 2>(y, W + 4 * HH, bb + 4 * 256, mbufa,
                              49152, 256, 256, 0, blockIdx.x * 128, blockIdx.y * 128);
  } else {
    int lid = (blockIdx.x - 384) * 2 + blockIdx.y;  // 0..255
    gemm_body<128, 128, 2, 2>(x, W, bb, afused,
                              4096, 1024, 256, 0, (lid >> 3) * 128, (lid & 7) * 128);
  }
}

// merged line gates + chunk-0 m/u3 GEMM: grid (384, 9)
__global__ __launch_bounds__(256) void line_gates_kernel(
    const bfu* __restrict__ y, const bfu* __restrict__ z,
    const bfu* __restrict__ W, const bfu* __restrict__ bb,
    bfu* __restrict__ lfused, bfu* __restrict__ mch0, bfu* __restrict__ u3c0,
    const int* __restrict__ loff)
{
  if (blockIdx.y < 6) {
    gemm_body<128, 128, 2, 2>(y, W, bb, lfused,
                              49152, 768, 256, 0, blockIdx.x * 128, blockIdx.y * 128);
  } else if (blockIdx.y < 8) {
    int cnt = loff[CHN];
    int m0 = blockIdx.x * 128;
    if (blockIdx.x >= CHCAP / 128 || m0 >= cnt) return;
    gemm_body<128, 128, 2, 2>(z, W + 4 * HH, bb + 4 * 256, mch0,
                              cnt, 256, 256, 0, m0, (blockIdx.y - 6) * 128);
  } else {
    if (blockIdx.x >= 64) return;
    gemm_body<128, 128, 2, 2>(y, W + 3 * HH, bb + 3 * 256, u3c0,
                              CHN, 256, 256, 0, (blockIdx.x & 31) * 128, (blockIdx.x >> 5) * 128);
  }
}

// --------------------------------------------- cos / bondlength precompute ----
__global__ __launch_bounds__(256) void cosbl_kernel(
    const float* __restrict__ r, const int* __restrict__ lsrc_p,
    const int* __restrict__ ldst_p, float* __restrict__ cosv,
    float* __restrict__ bl, int T, int E)
{
  int idx = blockIdx.x * 256 + threadIdx.x;
  if (idx < T) {
    int e1 = lsrc_p[idx], e2 = ldst_p[idx];
    float ax = -r[e1 * 3 + 0], ay = -r[e1 * 3 + 1], az = -r[e1 * 3 + 2];
    float bx =  r[e2 * 3 + 0], by =  r[e2 * 3 + 1], bz =  r[e2 * 3 + 2];
    float dot = ax * bx + ay * by + az * bz;
    float na = sqrtf(ax * ax + ay * ay + az * az);
    float nb = sqrtf(bx * bx + by * by + bz * bz);
    float c = dot / (na * nb);
    cosv[idx] = fminf(1.f, fmaxf(-1.f, c));
  } else if (idx < T + E) {
    int e = idx - T;
    float x = r[e * 3 + 0], yv = r[e * 3 + 1], zv = r[e * 3 + 2];
    bl[e] = sqrtf(x * x + yv * yv + zv * zv);
  }
}

// ------------------------- MLP1 fused: rbf(in staging) @ W1 + b1 -> LN64+SiLU
template<int KP, int BINS, int IS_ANG>
__global__ __launch_bounds__(256) void mlp1_ln_kernel(
    const float* __restrict__ v, const bfu* __restrict__ Bt,
    const bfu* __restrict__ bias, const bfu* __restrict__ lns,
    const bfu* __restrict__ lnb, bfu* __restrict__ outp, int M)
{
  constexpr int LDT = KP + 8;
  __shared__ bfu As[128 * LDT];
  const int tid = threadIdx.x, wave = tid >> 6, lane = tid & 63;
  const int lrow = lane & 15, kq = (lane >> 4) * 8;
  const int m0 = blockIdx.x * 128;

  for (int idx = tid; idx < 128 * (KP / 8); idx += 256) {
    int row = idx / (KP / 8), kc = (idx % (KP / 8)) * 8;
    float val = v[m0 + row];
    short8 pack;
#pragma unroll
    for (int jj = 0; jj < 8; ++jj) {
      int k = kc + jj;
      float e = 0.f;
      if (k < BINS) {
        float center = IS_ANG ? (-1.f + k * (2.f / 39.f)) : (k * (8.f / 79.f));
        float d = val - center;
        e = __expf((IS_ANG ? -19.5f : -9.875f) * d * d);
      }
      pack[jj] = (short)f2bf(e);
    }
    *(short8*)(void*)(As + row * LDT + kc) = pack;
  }
  __syncthreads();

  floatx4 acc[2][4];
#pragma unroll
  for (int i = 0; i < 2; ++i)
#pragma unroll
    for (int j = 0; j < 4; ++j) acc[i][j] = (floatx4){0.f, 0.f, 0.f, 0.f};
#pragma unroll
  for (int ks = 0; ks < KP / 32; ++ks) {
    short8 Af[2], Bf[4];
#pragma unroll
    for (int j = 0; j < 4; ++j)
      Bf[j] = *(const short8*)(const void*)(Bt + (size_t)(j * 16 + lrow) * KP + ks * 32 + kq);
#pragma unroll
    for (int i = 0; i < 2; ++i)
      Af[i] = *(const short8*)(const void*)(As + (wave * 32 + i * 16 + lrow) * LDT + ks * 32 + kq);
#pragma unroll
    for (int i = 0; i < 2; ++i)
#pragma unroll
      for (int j = 0; j < 4; ++j)
        acc[i][j] = __builtin_amdgcn_mfma_f32_16x16x32_bf16(Af[i], Bf[j], acc[i][j], 0, 0, 0);
  }

  const int rquad = lane >> 4, cin = lane & 15;
  float bj[4], sj[4], lj[4];
#pragma unroll
  for (int j = 0; j < 4; ++j) {
    bj[j] = bf2f(bias[j * 16 + cin]);
    sj[j] = bf2f(lns[j * 16 + cin]);
    lj[j] = bf2f(lnb[j * 16 + cin]);
  }
#pragma unroll
  for (int i = 0; i < 2; ++i) {
#pragma unroll
    for (int rr = 0; rr < 4; ++rr) {
      int row = m0 + wave * 32 + i * 16 + rquad * 4 + rr;
      float pre[4], s = 0.f, q = 0.f;
#pragma unroll
      for (int j = 0; j < 4; ++j) {
        pre[j] = acc[i][j][rr] + bj[j];
        s += pre[j]; q += pre[j] * pre[j];
      }
#pragma unroll
      for (int mm = 1; mm < 16; mm <<= 1) { s += __shfl_xor(s, mm); q += __shfl_xor(q, mm); }
      float mean = s * (1.f / 64.f);
      float rstd = rsqrtf(fmaxf(q * (1.f / 64.f) - mean * mean, 0.f) + 1e-5f);
#pragma unroll
      for (int j = 0; j < 4; ++j) {
        float u = (pre[j] - mean) * rstd * sj[j] + lj[j];
        outp[(size_t)row * 64 + j * 16 + cin] = f2bf(fsilu(u));
      }
    }
  }
}

// ------------- MLP2 fused: emb[M,64] @ W2 + b2 -> LN256+SiLU -> out[M,256]
__global__ __launch_bounds__(256) void mlp2_ln_kernel(
    const bfu* __restrict__ A, const bfu* __restrict__ Bt,
    const bfu* __restrict__ bias, const bfu* __restrict__ lns,
    const bfu* __restrict__ lnb, bfu* __restrict__ outp, int M)
{
  __shared__ float part[64 * 8];
  const int tid = threadIdx.x, wave = tid >> 6, lane = tid & 63;
  const int lrow = lane & 15, kq = (lane >> 4) * 8;
  const int m0 = blockIdx.x * 64;

  short8 Bf[2][4];
#pragma unroll
  for (int s = 0; s < 2; ++s)
#pragma unroll
    for (int j = 0; j < 4; ++j)
      Bf[s][j] = *(const short8*)(const void*)(
          Bt + (size_t)(wave * 64 + j * 16 + lrow) * 64 + s * 32 + kq);

  floatx4 acc[4][4];
#pragma unroll
  for (int i = 0; i < 4; ++i)
#pragma unroll
    for (int j = 0; j < 4; ++j) acc[i][j] = (floatx4){0.f, 0.f, 0.f, 0.f};
#pragma unroll
  for (int s = 0; s < 2; ++s) {
    short8 Af[4];
#pragma unroll
    for (int i = 0; i < 4; ++i)
      Af[i] = *(const short8*)(const void*)(
          A + (size_t)(m0 + i * 16 + lrow) * 64 + s * 32 + kq);
#pragma unroll
    for (int i = 0; i < 4; ++i)
#pragma unroll
      for (int j = 0; j < 4; ++j)
        acc[i][j] = __builtin_amdgcn_mfma_f32_16x16x32_bf16(Af[i], Bf[s][j], acc[i][j], 0, 0, 0);
  }

  const int rquad = lane >> 4, cin = lane & 15;
  float bj[4], sj[4], lj[4];
#pragma unroll
  for (int j = 0; j < 4; ++j) {
    int col = wave * 64 + j * 16 + cin;
    bj[j] = bf2f(bias[col]); sj[j] = bf2f(lns[col]); lj[j] = bf2f(lnb[col]);
  }
#pragma unroll
  for (int i = 0; i < 4; ++i) {
#pragma unroll
    for (int rr = 0; rr < 4; ++rr) {
      float s = 0.f, q = 0.f;
#pragma unroll
      for (int j = 0; j < 4; ++j) {
        float p = acc[i][j][rr] + bj[j];
        s += p; q += p * p;
      }
#pragma unroll
      for (int mm = 1; mm < 16; mm <<= 1) { s += __shfl_xor(s, mm); q += __shfl_xor(q, mm); }
      if (cin == 0) {
        int row = i * 16 + rquad * 4 + rr;
        part[row * 8 + wave * 2] = s;
        part[row * 8 + wave * 2 + 1] = q;
      }
    }
  }
  __syncthreads();
#pragma unroll
  for (int i = 0; i < 4; ++i) {
#pragma unroll
    for (int rr = 0; rr < 4; ++rr) {
      int row = i * 16 + rquad * 4 + rr;
      float s = part[row * 8] + part[row * 8 + 2] + part[row * 8 + 4] + part[row * 8 + 6];
      float q = part[row * 8 + 1] + part[row * 8 + 3] + part[row * 8 + 5] + part[row * 8 + 7];
      float mean = s * (1.f / 256.f);
      float rstd = rsqrtf(fmaxf(q * (1.f / 256.f) - mean * mean, 0.f) + 1e-5f);
#pragma unroll
      for (int j = 0; j < 4; ++j) {
        float u = (acc[i][j][rr] + bj[j] - mean) * rstd * sj[j] + lj[j];
        outp[(size_t)(m0 + row) * 256 + wave * 64 + j * 16 + cin] = f2bf(fsilu(u));
      }
    }
  }
}

// ----------------------------------------------------------- CSR build ----
__global__ __launch_bounds__(256) void count_kernel(
    const int* __restrict__ d, int* __restrict__ cnt, int ne) {
  int i = blockIdx.x * 256 + threadIdx.x;
  if (i < ne) atomicAdd(&cnt[d[i]], 1);
}
__global__ __launch_bounds__(256) void scan_kernel(
    const int* __restrict__ cnt, int* __restrict__ off, int n) {
  __shared__ int ssum[256];
  __shared__ int sbase[257];
  int t = threadIdx.x;
  int strip = (n + 255) / 256;
  int lo = t * strip, hi = lo + strip; if (hi > n) hi = n; if (lo > n) lo = n;
  int s = 0;
  for (int i = lo; i < hi; ++i) s += cnt[i];
  ssum[t] = s;
  __syncthreads();
  if (t == 0) {
    int run = 0;
    for (int i = 0; i < 256; ++i) { sbase[i] = run; run += ssum[i]; }
    sbase[256] = run;
  }
  __syncthreads();
  int run = sbase[t];
  for (int i = lo; i < hi; ++i) { off[i] = run; run += cnt[i]; }
  if (t == 0) off[n] = sbase[256];
}
__global__ __launch_bounds__(256) void copy_kernel(
    const int* __restrict__ a, int* __restrict__ b, int n) {
  int i = blockIdx.x * 256 + threadIdx.x;
  if (i < n) b[i] = a[i];
}
__global__ __launch_bounds__(256) void fill_kernel(
    const int* __restrict__ d, int* __restrict__ cur, int* __restrict__ ids, int ne) {
  int i = blockIdx.x * 256 + threadIdx.x;
  if (i < ne) ids[atomicAdd(&cur[d[i]], 1)] = i;
}
__global__ __launch_bounds__(256) void fill2_kernel(
    const int* __restrict__ ldst, const int* __restrict__ lsrc, int* __restrict__ cur,
    int* __restrict__ lsrc_p, int* __restrict__ ldst_p, int ne) {
  int i = blockIdx.x * 256 + threadIdx.x;
  if (i >= ne) return;
  int d = ldst[i];
  int pos = atomicAdd(&cur[d], 1);
  lsrc_p[pos] = lsrc[i];
  ldst_p[pos] = d;
}

// ------------------------------------------------------ weight transpose ----
__global__ __launch_bounds__(256) void transpose_pad_kernel(
    const void* __restrict__ W, bfu* __restrict__ Wt, int K, int N, int Kp,
    const int* __restrict__ mode)
{
  int idx = blockIdx.x * 256 + threadIdx.x;
  if (idx >= N * Kp) return;
  int n = idx / Kp, k = idx - n * Kp;
  bfu v = 0;
  if (k < K) {
    size_t si = (size_t)k * N + n;
    v = (*mode) ? f2bf(((const float*)W)[si]) : ((const bfu*)W)[si];
  }
  Wt[idx] = v;
}
// unified slot order: [W0, W4, W1, W3, W2] -> gates [g0|u4|g1(|u3)], m slot 4
__device__ __forceinline__ int slot2mat(int slot) {
  const int m[5] = {0, 4, 1, 3, 2};
  return m[slot];
}
__global__ __launch_bounds__(256) void transpose_eggc_kernel(
    const void* __restrict__ W, bfu* __restrict__ Wt, const int* __restrict__ mode)
{
  int bs = blockIdx.y;
  int blk = bs / 5, slot = bs - blk * 5;
  int mat = slot2mat(slot);
  int idx = blockIdx.x * 256 + threadIdx.x;
  int n = idx >> 8, k = idx & 255;
  size_t si = ((size_t)(blk * 5 + mat) * 256 + k) * 256 + n;
  bfu v = (*mode) ? f2bf(((const float*)W)[si]) : ((const bfu*)W)[si];
  Wt[((size_t)bs * 256 + n) * 256 + k] = v;
}
__global__ __launch_bounds__(256) void bias_perm_kernel(
    const void* __restrict__ B, bfu* __restrict__ Bp, const int* __restrict__ mode)
{
  int i = blockIdx.x * 256 + threadIdx.x;
  int bs = i >> 8, c = i & 255;
  int blk = bs / 5, slot = bs - blk * 5;
  int mat = slot2mat(slot);
  size_t si = (size_t)(blk * 5 + mat) * 256 + c;
  Bp[i] = (*mode) ? f2bf(((const float*)B)[si]) : ((const bfu*)B)[si];
}

// ------------------- atom single-pass agg (edge update in node loop) ------
// af layout: [g0|u4|g1|u3] stride 1024; g0,u4 adjacent -> per edge 1 streak.
__global__ __launch_bounds__(256) void atom_fused_kernel(
    const bfu* __restrict__ mbuf, const bfu* __restrict__ af,
    const int* __restrict__ src,
    bfu* __restrict__ X, bfu* __restrict__ Y,
    const int* __restrict__ aoff, const int* __restrict__ aids,
    int do_edge,
    const bfu* __restrict__ lns, const bfu* __restrict__ lnb,
    const bfu* __restrict__ les, const bfu* __restrict__ leb)
{
  int wave = threadIdx.x >> 6, lane = threadIdx.x & 63;
  int half = lane >> 5, c8 = (lane & 31) * 8;
  int n = blockIdx.x * 4 + wave;
  int p0 = aoff[n], p1 = aoff[n + 1];
  f8 g1 = ld8(af + (size_t)n * 1024 + 512 + c8);
  f8 esg = {}, ebb = {};
  if (do_edge) { esg = ld8(les + c8); ebb = ld8(leb + c8); }
  f8 num = {}, den = {};
  for (int p = p0 + half; p < p1; p += 2) {
    int id = aids[p], sx = src[id];
    f8 m = add8(add8(ld8(mbuf + (size_t)id * 256 + c8),
                     ld8(af + (size_t)sx * 1024 + c8)), g1);
    f8 sg = sig8(m);
    f8 u4 = ld8(af + (size_t)sx * 1024 + 256 + c8);
#pragma unroll
    for (int i = 0; i < 8; ++i) {
      num.v[i] += sg.v[i] * u4.v[i];
      den.v[i] += sg.v[i];
    }
    if (do_edge) {
      f8 sil = lnsilu8(m, esg, ebb);
      bfu* op = Y + (size_t)id * 256 + c8;
      st8(op, add8(sil, ld8(op)));
    }
  }
#pragma unroll
  for (int i = 0; i < 8; ++i) {
    num.v[i] += __shfl_xor(num.v[i], 32);
    den.v[i] += __shfl_xor(den.v[i], 32);
  }
  f8 u3 = ld8(af + (size_t)n * 1024 + 768 + c8);
  f8 pre;
#pragma unroll
  for (int i = 0; i < 8; ++i)
    pre.v[i] = u3.v[i] + num.v[i] / (den.v[i] + 1e-6f);
  f8 sil = lnsilu8(pre, ld8(lns + c8), ld8(lnb + c8));
  if (half == 0) {
    bfu* op = X + (size_t)n * 256 + c8;
    st8(op, add8(sil, ld8(op)));
  }
}

// ------------------- line single-pass agg (edge update in node loop) ------
// lf layout: [g0|u4|g1] stride 768; m rows contiguous (ldst-sorted).
__global__ __launch_bounds__(256) void line_fused_kernel(
    const bfu* __restrict__ mchunk, const bfu* __restrict__ lf,
    const bfu* __restrict__ u3c,
    const int* __restrict__ loff, const int* __restrict__ lsrc_p,
    bfu* __restrict__ Z, bfu* __restrict__ Y,
    int n0, int do_edge,
    const bfu* __restrict__ lns, const bfu* __restrict__ lnb,
    const bfu* __restrict__ les, const bfu* __restrict__ leb)
{
  int wave = threadIdx.x >> 6, lane = threadIdx.x & 63;
  int half = lane >> 5, c8 = (lane & 31) * 8;
  int n = n0 + blockIdx.x * 4 + wave;
  int p0 = loff[n], p1 = loff[n + 1], base = loff[n0];
  f8 g1 = ld8(lf + (size_t)n * 768 + 512 + c8);
  f8 esg = {}, ebb = {};
  if (do_edge) { esg = ld8(les + c8); ebb = ld8(leb + c8); }
  f8 num = {}, den = {};
  for (int p = p0 + half; p < p1; p += 2) {
    int sx = lsrc_p[p];
    f8 m = add8(add8(ld8(mchunk + (size_t)(p - base) * 256 + c8),
                     ld8(lf + (size_t)sx * 768 + c8)), g1);
    f8 sg = sig8(m);
    f8 u4 = ld8(lf + (size_t)sx * 768 + 256 + c8);
#pragma unroll
    for (int i = 0; i < 8; ++i) {
      num.v[i] += sg.v[i] * u4.v[i];
      den.v[i] += sg.v[i];
    }
    if (do_edge) {
      f8 sil = lnsilu8(m, esg, ebb);
      bfu* op = Z + (size_t)p * 256 + c8;
      st8(op, add8(sil, ld8(op)));
    }
  }
#pragma unroll
  for (int i = 0; i < 8; ++i) {
    num.v[i] += __shfl_xor(num.v[i], 32);
    den.v[i] += __shfl_xor(den.v[i], 32);
  }
  f8 u3 = ld8(u3c + (size_t)(n - n0) * 256 + c8);
  f8 pre;
#pragma unroll
  for (int i = 0; i < 8; ++i)
    pre.v[i] = u3.v[i] + num.v[i] / (den.v[i] + 1e-6f);
  f8 sil = lnsilu8(pre, ld8(lns + c8), ld8(lnb + c8));
  if (half == 0) {
    bfu* op = Y + (size_t)n * 256 + c8;
    st8(op, add8(sil, ld8(op)));
  }
}

// ----------------------------------------------------------- atom init ----
__global__ __launch_bounds__(256) void atom_init_kernel(
    const bfu* __restrict__ af, const bfu* __restrict__ W, const bfu* __restrict__ bias,
    const bfu* __restrict__ lns, const bfu* __restrict__ lnb, bfu* __restrict__ X)
{
  __shared__ float sm[4];
  int row = blockIdx.x, c = threadIdx.x;
  float acc = bf2f(bias[c]);
  for (int k = 0; k < 92; ++k)
    acc += bf2f(af[row * 92 + k]) * bf2f(W[k * 256 + c]);
  float mean = block_sum256(acc, sm) * (1.f / 256.f);
  float d = acc - mean;
  float var = block_sum256(d * d, sm) * (1.f / 256.f);
  float u = d * rsqrtf(var + 1e-5f) * bf2f(lns[c]) + bf2f(lnb[c]);
  X[(size_t)row * 256 + c] = f2bf(fsilu(u));
}

// --------------------------------------------------------------- final ----
__global__ __launch_bounds__(256) void final_kernel(
    const bfu* __restrict__ X, const bfu* __restrict__ fcW, const bfu* __restrict__ fcb,
    void* __restrict__ out, float* __restrict__ acc, const int* __restrict__ mode)
{
  int row = blockIdx.x * 4 + (threadIdx.x >> 6);
  int lane = threadIdx.x & 63;
  float s = 0.f;
#pragma unroll
  for (int k = 0; k < 4; ++k)
    s += bf2f(X[(size_t)row * 256 + lane + k * 64]) * bf2f(fcW[lane + k * 64]);
#pragma unroll
  for (int o = 32; o; o >>= 1) s += __shfl_down(s, o);
  if (lane == 0) {
    float v = s + bf2f(fcb[0]);
    if (*mode) ((float*)out)[1 + row] = v;
    else       ((bfu*)out)[1 + row] = f2bf(v);
    atomicAdd(acc, v);
  }
}
__global__ void mean_kernel(const float* __restrict__ acc, void* __restrict__ out,
                            const int* __restrict__ mode) {
  if (threadIdx.x == 0) {
    float v = acc[0] * (1.f / 4096.f);
    if (*mode) ((float*)out)[0] = v;
    else       ((bfu*)out)[0] = f2bf(v);
  }
}
__global__ void dbg_kernel(void* __restrict__ out, float v) {
  if (threadIdx.x == 0) { ((bfu*)out)[0] = f2bf(v); }
}

// ---------------------------------------------------------------- host ----
extern "C" void kernel_launch(void* const* d_in, const int* in_sizes, int n_in,
                              void* d_out, int out_size, void* d_ws, size_t ws_size,
                              hipStream_t stream) {
  const int N = 4096, E = 49152, T = 262144, H = 256;

  const int* src  = (const int*)d_in[2];
  const int* dst  = (const int*)d_in[3];
  const int* lsrc = (const int*)d_in[4];
  const int* ldst = (const int*)d_in[5];

  // ---- workspace carve (round-11 proven) ----
  char* bp = (char*)d_ws;
  size_t off = 0;
  auto carve = [&](size_t bytes) -> char* {
    char* q = bp + off;
    off = (off + bytes + 255) & ~(size_t)255;
    return q;
  };
  bfu* x       = (bfu*)carve((size_t)N * H * 2);
  bfu* y       = (bfu*)carve((size_t)E * H * 2);
  bfu* z       = (bfu*)carve((size_t)T * H * 2);       // ldst-sorted
  bfu* reg     = (bfu*)carve((size_t)E * 768 * 2);
  bfu* u3c     = (bfu*)carve((size_t)CHN * H * 2);
  bfu* mchunk  = (bfu*)carve((size_t)CHCAP * H * 2);
  bfu* WtE     = (bfu*)carve((size_t)60 * H * H * 2);  // slot-ordered
  bfu* ebp     = (bfu*)carve((size_t)12 * 5 * H * 2);
  bfu* Wt_a1   = (bfu*)carve(64 * 64 * 2);
  bfu* Wt_a2   = (bfu*)carve(256 * 64 * 2);
  bfu* Wt_e1   = (bfu*)carve(64 * 128 * 2);
  bfu* Wt_e2   = (bfu*)carve(256 * 64 * 2);
  int* aoff    = (int*)carve((size_t)(N + 1) * 4);
  int* aids    = (int*)carve((size_t)E * 4);
  int* loff    = (int*)carve((size_t)(E + 1) * 4);
  int* lsrc_p  = (int*)carve((size_t)T * 4);
  int* ldst_p  = (int*)carve((size_t)T * 4);
  int* cursors = (int*)carve((size_t)E * 4);
  float* macc  = (float*)carve(256);
  int* mode    = (int*)carve(256);
  bfu* par_c   = (bfu*)carve(8192 * 2);
  bfu* els_c   = (bfu*)carve((size_t)12 * 2 * H * 2);
  bfu* elb_c   = (bfu*)carve((size_t)12 * 2 * H * 2);

  if (off > ws_size) {
    hipMemsetAsync(d_out, 0, (size_t)out_size * 2, stream);
    dbg_kernel<<<1, 64, 0, stream>>>(d_out, (float)(ws_size >> 20));
    return;
  }

  // early-phase scratch in reg tail
  char* tail = (char*)reg + (size_t)52 * 1024 * 1024;
  bfu* af_c  = (bfu*)tail;                 tail += ((size_t)N * 92 * 2 + 255) & ~255ull;
  float* r_f = (float*)tail;               tail += ((size_t)E * 3 * 4 + 255) & ~255ull;
  float* cosv = (float*)tail;              tail += ((size_t)T * 4 + 255) & ~255ull;
  float* blv = (float*)tail;               tail += ((size_t)E * 4 + 255) & ~255ull;
  bfu* atW_c = (bfu*)tail;

  // packed small params
  bfu* atom_b_c   = par_c + 0;
  bfu* atom_lns_c = par_c + 256;
  bfu* atom_lnb_c = par_c + 512;
  bfu* e_b1_c     = par_c + 768;
  bfu* e_l1s_c    = par_c + 832;
  bfu* e_l1b_c    = par_c + 896;
  bfu* e_b2_c     = par_c + 1024;
  bfu* e_l2s_c    = par_c + 1280;
  bfu* e_l2b_c    = par_c + 1536;
  bfu* a_b1_c     = par_c + 1792;
  bfu* a_l1s_c    = par_c + 1856;
  bfu* a_l1b_c    = par_c + 1920;
  bfu* a_b2_c     = par_c + 2048;
  bfu* a_l2s_c    = par_c + 2304;
  bfu* a_l2b_c    = par_c + 2560;
  bfu* fcW_c      = par_c + 2816;
  bfu* fcb_c      = par_c + 3072;

  // overlays within reg
  bfu* lfused = reg;                        // line: [E,768] g0|u4|g1
  bfu* afused = reg;                        // atom: [N,1024] g0|u4|g1|u3
  bfu* mbufa  = reg + (size_t)N * 1024;     // atom: [E,256] m_raw
  bfu* emb_t  = reg;                        // early: [T,64]
  bfu* emb_e  = reg + (size_t)T * 64;       // early: [E,64]

  // ---- dtype probe + param conversion ----
  probe_kernel<<<1, 64, 0, stream>>>((const unsigned*)d_in[8], mode);
  CvtPack pk;
  int ii = 0;
  auto add = [&](int idx, bfu* dstp, int n) { pk.e[ii++] = {d_in[idx], dstp, n}; };
  add(7, atom_b_c, 256);  add(8, atom_lns_c, 256); add(9, atom_lnb_c, 256);
  add(11, e_b1_c, 64);    add(12, e_l1s_c, 64);    add(13, e_l1b_c, 64);
  add(15, e_b2_c, 256);   add(16, e_l2s_c, 256);   add(17, e_l2b_c, 256);
  add(19, a_b1_c, 64);    add(20, a_l1s_c, 64);    add(21, a_l1b_c, 64);
  add(23, a_b2_c, 256);   add(24, a_l2s_c, 256);   add(25, a_l2b_c, 256);
  add(30, fcW_c, 256);    add(31, fcb_c, 1);
  add(28, els_c, 12 * 2 * 256);
  add(29, elb_c, 12 * 2 * 256);
  add(6, atW_c, 92 * 256);
  cvt_batch_kernel<<<dim3(92, 20), 256, 0, stream>>>(pk, mode);
  cvt_kernel<<<(N * 92 + 255) / 256, 256, 0, stream>>>(d_in[0], af_c, N * 92, mode);
  cvtf_kernel<<<(E * 3 + 255) / 256, 256, 0, stream>>>(d_in[1], r_f, E * 3, mode);

  // ---- CSR builds + direct permuted indices ----
  hipMemsetAsync(cursors, 0, (size_t)N * 4, stream);
  count_kernel<<<E / 256, 256, 0, stream>>>(dst, cursors, E);
  scan_kernel<<<1, 256, 0, stream>>>(cursors, aoff, N);
  copy_kernel<<<(N + 255) / 256, 256, 0, stream>>>(aoff, cursors, N);
  fill_kernel<<<E / 256, 256, 0, stream>>>(dst, cursors, aids, E);

  hipMemsetAsync(cursors, 0, (size_t)E * 4, stream);
  count_kernel<<<T / 256, 256, 0, stream>>>(ldst, cursors, T);
  scan_kernel<<<1, 256, 0, stream>>>(cursors, loff, E);
  copy_kernel<<<(E + 255) / 256, 256, 0, stream>>>(loff, cursors, E);
  fill2_kernel<<<T / 256, 256, 0, stream>>>(ldst, lsrc, cursors, lsrc_p, ldst_p, T);

  // ---- weight transposes ----
  transpose_eggc_kernel<<<dim3(256, 60), 256, 0, stream>>>(d_in[26], WtE, mode);
  bias_perm_kernel<<<60, 256, 0, stream>>>(d_in[27], ebp, mode);
  transpose_pad_kernel<<<16, 256, 0, stream>>>(d_in[18], Wt_a1, 40, 64, 64, mode);
  transpose_pad_kernel<<<64, 256, 0, stream>>>(d_in[22], Wt_a2, 64, 256, 64, mode);
  transpose_pad_kernel<<<32, 256, 0, stream>>>(d_in[10], Wt_e1, 80, 64, 128, mode);
  transpose_pad_kernel<<<64, 256, 0, stream>>>(d_in[14], Wt_e2, 64, 256, 64, mode);

  // ---- cos / bondlength, then fused MLP pipelines ----
  cosbl_kernel<<<(T + E + 255) / 256, 256, 0, stream>>>(r_f, lsrc_p, ldst_p, cosv, blv, T, E);
  mlp1_ln_kernel<64, 40, 1><<<T / 128, 256, 0, stream>>>(
      cosv, Wt_a1, a_b1_c, a_l1s_c, a_l1b_c, emb_t, T);
  mlp2_ln_kernel<<<T / 64, 256, 0, stream>>>(emb_t, Wt_a2, a_b2_c, a_l2s_c, a_l2b_c, z, T);
  mlp1_ln_kernel<128, 80, 0><<<E / 128, 256, 0, stream>>>(
      blv, Wt_e1, e_b1_c, e_l1s_c, e_l1b_c, emb_e, E);
  mlp2_ln_kernel<<<E / 64, 256, 0, stream>>>(emb_e, Wt_e2, e_b2_c, e_l2s_c, e_l2b_c, y, E);

  // ---- x = MLP(atom_features) ----
  atom_init_kernel<<<N, 256, 0, stream>>>(af_c, atW_c, atom_b_c, atom_lns_c, atom_lnb_c, x);

  // ---- EGGC blocks ----
  auto atom_eggc = [&](int blk, int do_edge) {
    const bfu* W  = WtE + (size_t)blk * 5 * HH;
    const bfu* bb = ebp + (size_t)blk * 5 * H;
    const bfu* ls = els_c + (size_t)blk * 2 * H;
    const bfu* lb = elb_c + (size_t)blk * 2 * H;
    atom_gemm_kernel<<<dim3(512, 2), 256, 0, stream>>>(x, y, W, bb, afused, mbufa);
    atom_fused_kernel<<<N / 4, 256, 0, stream>>>(
        mbufa, afused, src, x, y, aoff, aids, do_edge, ls, lb, ls + H, lb + H);
  };

  auto line_eggc = [&](int blk, int do_edge) {
    const bfu* W  = WtE + (size_t)blk * 5 * HH;
    const bfu* bb = ebp + (size_t)blk * 5 * H;
    const bfu* ls = els_c + (size_t)blk * 2 * H;
    const bfu* lb = elb_c + (size_t)blk * 2 * H;
    // gates [E,768] + chunk-0 m/u3 in one launch
    line_gates_kernel<<<dim3(384, 9), 256, 0, stream>>>(
        y, z, W, bb, lfused, mchunk, u3c, loff);
    for (int c = 0; c < E / CHN; ++c) {
      int n0 = c * CHN;
      line_fused_kernel<<<CHN / 4, 256, 0, stream>>>(
          mchunk, lfused, u3c, loff, lsrc_p, z, y, n0, do_edge,
          ls, lb, ls + H, lb + H);
      if (c + 1 < E / CHN)
        line_gemm_kernel<<<dim3(CHCAP / 128, 3), 256, 0, stream>>>(
            z, y, W, bb, mchunk, u3c, loff, n0 + CHN, n0 + 2 * CHN);
    }
  };

  for (int i = 0; i < 4; ++i) {
    atom_eggc(2 * i, 1);
    line_eggc(2 * i + 1, i < 3);   // block 7's z-update is dead
  }
  for (int i = 0; i < 4; ++i)
    atom_eggc(8 + i, i < 3);       // block 11's y-update is dead

  // ---- output ----
  hipMemsetAsync(macc, 0, 4, stream);
  final_kernel<<<N / 4, 256, 0, stream>>>(x, fcW_c, fcb_c, d_out, macc, mode);
  mean_kernel<<<1, 64, 0, stream>>>(macc, d_out, mode);
}